// Round 13
// baseline (1298.847 us; speedup 1.0000x reference)
//
#include <hip/hip_runtime.h>
#include <math.h>

#define N_NODES 50000
#define N_EDGES 800000
#define H 96
#define QKV_N 288

#define NPB1 32   // nodes per block, qkv kernel
#define NPB3 4    // nodes per block, node kernel (gather fallback, R7-proven)
#define NPB3B 8   // nodes per block, node kernel (big path, streaming)
#define NPA 32    // nodes per agg block

typedef __attribute__((ext_vector_type(8))) short short8;   // 8 bf16 = 4 VGPRs
typedef __attribute__((ext_vector_type(4))) float f32x4;    // MFMA accumulator

// float -> bf16 (RNE) — used for storage roundings (vbf, cobf, eh tile).
__device__ __forceinline__ short f2bf(float f) {
    union { float f; unsigned u; } v; v.f = f;
    unsigned r = v.u + 0x7FFFu + ((v.u >> 16) & 1u);
    return (short)(r >> 16);
}
__device__ __forceinline__ float bf2f(unsigned short h) {
    union { unsigned u; float f; } v; v.u = ((unsigned)h) << 16;
    return v.f;
}

// TRUNCATION hi/lo split (R12-proven): hi = top 16 bits (exact); residual is
// exactly representable; lo = trunc-bf16(residual). Dropped err <= 2^-16|f|.
__device__ __forceinline__ void ld_frag_split(const float* __restrict__ p,
                                              short8& hi, short8& lo) {
    float4 a = *(const float4*)p;
    float4 b = *(const float4*)(p + 4);
    float f[8] = {a.x, a.y, a.z, a.w, b.x, b.y, b.z, b.w};
    #pragma unroll
    for (int j = 0; j < 8; ++j) {
        union { float f; unsigned u; } v; v.f = f[j];
        hi[j] = (short)(v.u >> 16);
        union { unsigned u; float f; } h; h.u = v.u & 0xFFFF0000u;
        union { float f; unsigned u; } l; l.f = f[j] - h.f;
        lo[j] = (short)(l.u >> 16);
    }
}

// ---------------------------------------------------------------------------
// Kernel 1: qkv[n, t] = dot(x[n, :], qkv_w[t, :]) + qkv_b[t]   (t < 288)
// Also emits V as bf16 (vbf) for the L2-resident agg gather.
// ---------------------------------------------------------------------------
__global__ __launch_bounds__(QKV_N) void qkv_kernel(
    const float* __restrict__ x, const float* __restrict__ qw,
    const float* __restrict__ qb, float* __restrict__ qkv,
    unsigned short* __restrict__ vbf)
{
    __shared__ __align__(16) float xs[H];
    const int t = threadIdx.x;

    float w[H];
    #pragma unroll
    for (int k4 = 0; k4 < H; k4 += 4) {
        float4 v = *(const float4*)(qw + (size_t)t * H + k4);
        w[k4] = v.x; w[k4 + 1] = v.y; w[k4 + 2] = v.z; w[k4 + 3] = v.w;
    }
    const float bias = qb[t];

    const int n0 = blockIdx.x * NPB1;
    for (int nn = 0; nn < NPB1; ++nn) {
        const int node = n0 + nn;
        if (node >= N_NODES) break;          // block-uniform
        __syncthreads();
        if (t < H) xs[t] = x[(size_t)node * H + t];
        __syncthreads();
        float acc = bias;
        #pragma unroll
        for (int k4 = 0; k4 < H; k4 += 4) {
            float4 c = *(const float4*)(xs + k4);
            acc += c.x * w[k4] + c.y * w[k4 + 1] + c.z * w[k4 + 2] + c.w * w[k4 + 3];
        }
        qkv[(size_t)node * QKV_N + t] = acc;
        if (vbf && t >= 2 * H)
            vbf[(size_t)node * H + (t - 2 * H)] = (unsigned short)f2bf(acc);
    }
}

// ---------------------------------------------------------------------------
// CSR build: histogram -> scan -> scatter   (proven R4-R12)
// ---------------------------------------------------------------------------
__global__ __launch_bounds__(256) void hist_kernel(const int* __restrict__ eidx,
                                                   int* __restrict__ hist) {
    const int e = blockIdx.x * 256 + threadIdx.x;
    if (e < N_EDGES) atomicAdd(&hist[eidx[e]], 1);
}

#define SCAN_CH 49   // 1024*49 = 50176 >= 50000
__global__ __launch_bounds__(1024) void scan_kernel(int* __restrict__ hist,
                                                    int* __restrict__ rowptr) {
    __shared__ int sums[1024];
    const int t = threadIdx.x;
    const int st = t * SCAN_CH;
    int loc = 0;
    for (int k = 0; k < SCAN_CH; ++k) {
        const int i = st + k;
        if (i < N_NODES) loc += hist[i];
    }
    sums[t] = loc;
    __syncthreads();
    for (int off = 1; off < 1024; off <<= 1) {
        int add = (t >= off) ? sums[t - off] : 0;
        __syncthreads();
        sums[t] += add;
        __syncthreads();
    }
    int run = sums[t] - loc;     // exclusive prefix of this thread's chunk
    for (int k = 0; k < SCAN_CH; ++k) {
        const int i = st + k;
        if (i < N_NODES) {
            const int v = hist[i];
            rowptr[i] = run;
            hist[i]   = run;     // hist becomes the scatter cursor
            run += v;
        }
    }
    if (t == 1023) rowptr[N_NODES] = run;   // = N_EDGES
}

__global__ __launch_bounds__(256) void scatter_kernel(const int* __restrict__ eidx,
                                                      int* __restrict__ cursor,
                                                      int* __restrict__ bucket,
                                                      int* __restrict__ bsrc,
                                                      int* __restrict__ dstof) {
    const int e = blockIdx.x * 256 + threadIdx.x;
    if (e < N_EDGES) {
        const int dst = eidx[e];
        const int src = eidx[N_EDGES + e];
        const int pos = atomicAdd(&cursor[dst], 1);
        bucket[pos] = e;
        bsrc[pos]   = src;
        if (dstof) dstof[pos] = dst;
    }
}

// ---------------------------------------------------------------------------
// Kernel 2 (MFMA, bf16x3 trunc-split). R13's single change vs R12: the eh
// tile is stored as bf16 (25.6 KB LDS vs 50 KB) -> 6 blocks/CU vs 3.
// This read path is indirectly validated: R10's cobf (which passed via
// Output 0) was computed through exactly this bf16-eh structure.
// NO LN fusion (abandoned after R4/R10/R11 — eln stays separate).
// ---------------------------------------------------------------------------
#define TILE_E 64
#define EH_LDS 200   // ushort leading dim; 400 B/row keeps short8 16B-aligned

template <bool COBF>
__global__ __launch_bounds__(256) void edge_kernel(
    const float* __restrict__ conn, const int* __restrict__ eidx,
    const float* __restrict__ qkv,
    const float* __restrict__ ew, const float* __restrict__ eb,
    unsigned short* __restrict__ co_bf, float* __restrict__ out_e)
{
    __shared__ __align__(16) unsigned short eh2[TILE_E * EH_LDS];   // 25600 B

    const int t    = threadIdx.x;
    const int wave = t >> 6;
    const int lane = t & 63;
    const int lr   = lane & 15;
    const int lg16 = lane >> 4;

    // ---- B fragments (hi+lo): e_w rows are B^T rows ----
    short8 bwh[3][3], bwl[3][3];
    #pragma unroll
    for (int f = 0; f < 3; ++f) {
        const int tcol = 16 * (3 * wave + f) + lr;
        #pragma unroll
        for (int kc = 0; kc < 3; ++kc)
            ld_frag_split(ew + (size_t)tcol * H + 32 * kc + 8 * lg16,
                          bwh[f][kc], bwl[f][kc]);
    }

    const int e0 = blockIdx.x * TILE_E;

    f32x4 acc[4][3];
    #pragma unroll
    for (int mt = 0; mt < 4; ++mt)
        #pragma unroll
        for (int f = 0; f < 3; ++f)
            acc[mt][f] = (f32x4){0.f, 0.f, 0.f, 0.f};

    #pragma unroll
    for (int mt = 0; mt < 4; ++mt) {
        const int erow = e0 + 16 * mt + lr;
        short8 ah[3], al[3];
        #pragma unroll
        for (int kc = 0; kc < 3; ++kc)
            ld_frag_split(conn + (size_t)erow * H + 32 * kc + 8 * lg16,
                          ah[kc], al[kc]);
        #pragma unroll
        for (int f = 0; f < 3; ++f) {
            #pragma unroll
            for (int kc = 0; kc < 3; ++kc) {
                acc[mt][f] = __builtin_amdgcn_mfma_f32_16x16x32_bf16(
                                 ah[kc], bwl[f][kc], acc[mt][f], 0, 0, 0);
                acc[mt][f] = __builtin_amdgcn_mfma_f32_16x16x32_bf16(
                                 al[kc], bwh[f][kc], acc[mt][f], 0, 0, 0);
                acc[mt][f] = __builtin_amdgcn_mfma_f32_16x16x32_bf16(
                                 ah[kc], bwh[f][kc], acc[mt][f], 0, 0, 0);
            }
        }
    }

    // ---- write Eh (+bias) to LDS as RNE-bf16 (relative err only -> safe) ----
    #pragma unroll
    for (int mt = 0; mt < 4; ++mt) {
        #pragma unroll
        for (int f = 0; f < 3; ++f) {
            const int col = 16 * (3 * wave + f) + lr;
            const float bias = eb[col];
            #pragma unroll
            for (int r = 0; r < 4; ++r) {
                const int row = 16 * mt + 4 * lg16 + r;
                eh2[row * EH_LDS + col] = (unsigned short)f2bf(acc[mt][f][r] + bias);
            }
        }
    }
    __syncthreads();

    // ---- pointwise: lane q4 owns cols [24*q4, 24*q4+24) ----
    const int e_loc = t >> 2;
    const int q4    = t & 3;
    const int e     = e0 + e_loc;
    const int dst   = eidx[e];
    const int src   = eidx[N_EDGES + e];
    const float4* qQ4 = (const float4*)(qkv + (size_t)dst * QKV_N) + 6 * q4;
    const float4* qK4 = (const float4*)(qkv + (size_t)src * QKV_N + H) + 6 * q4;
    float4*          oe4 = (float4*)(out_e + (size_t)e * H) + 6 * q4;
    unsigned short*  cb  = COBF ? (co_bf + (size_t)e * H + 24 * q4) : nullptr;
    const unsigned short* ehr = &eh2[e_loc * EH_LDS + 24 * q4];

    // bulk bf16 LDS reads: 24 Ew + 24 Eb cols (16B-aligned short8)
    short8 w8[3], b8[3];
    #pragma unroll
    for (int j = 0; j < 3; ++j) {
        w8[j] = ((const short8*)ehr)[j];
        b8[j] = ((const short8*)(ehr + H))[j];
    }

    #pragma unroll
    for (int i = 0; i < 6; ++i) {
        const float4 q  = qQ4[i];
        const float4 k  = qK4[i];
        float4 co4;
        #pragma unroll
        for (int jj = 0; jj < 4; ++jj) {
            const int idx = 4 * i + jj;
            const float wv = bf2f((unsigned short)w8[idx >> 3][idx & 7]);
            const float bb = bf2f((unsigned short)b8[idx >> 3][idx & 7]);
            const float c1 = (q[jj] + k[jj]) * wv;
            const float c2 = copysignf(sqrtf(fabsf(c1)), c1);
            co4[jj] = fmaxf(c2 + bb, 0.f);
        }
        if (COBF) {
            ushort4 pk;
            pk.x = (unsigned short)f2bf(co4[0]);
            pk.y = (unsigned short)f2bf(co4[1]);
            pk.z = (unsigned short)f2bf(co4[2]);
            pk.w = (unsigned short)f2bf(co4[3]);
            *(ushort4*)(cb + 4 * i) = pk;
        } else {
            oe4[i] = co4;
        }
    }
}

// ---------------------------------------------------------------------------
// eln: out_e = LN(conn + co). COBF: co from bf16 co_bf; else in-place fp32.
// (R9/R12-verbatim, proven.)
// ---------------------------------------------------------------------------
template <bool COBF>
__global__ __launch_bounds__(256) void eln_kernel(
    const float* __restrict__ conn, const unsigned short* __restrict__ co_bf,
    const float* __restrict__ ln_g, const float* __restrict__ ln_b,
    float* __restrict__ out_e)
{
    const int tt   = blockIdx.x * 256 + threadIdx.x;
    const size_t e = (size_t)(tt >> 2);
    const int q4   = tt & 3;
    const float4* cn4 = (const float4*)(conn + e * H) + 6 * q4;
    float4*       oe4 = (float4*)(out_e + e * H) + 6 * q4;
    const float4* g4  = (const float4*)ln_g + 6 * q4;
    const float4* b4  = (const float4*)ln_b + 6 * q4;

    float4 v[6];
    float s = 0.f, s2 = 0.f;
    if (COBF) {
        const short8* cb8 = (const short8*)(co_bf + e * H + 24 * q4);
        #pragma unroll
        for (int j = 0; j < 3; ++j) {
            const short8 c8 = cb8[j];
            const float4 cA = cn4[2 * j];
            const float4 cB = cn4[2 * j + 1];
            #pragma unroll
            for (int k = 0; k < 4; ++k) {
                const float a = cA[k] + bf2f((unsigned short)c8[k]);
                const float b = cB[k] + bf2f((unsigned short)c8[4 + k]);
                v[2 * j][k] = a; v[2 * j + 1][k] = b;
                s += a + b; s2 += a * a + b * b;
            }
        }
    } else {
        #pragma unroll
        for (int i = 0; i < 6; ++i) {
            const float4 c = cn4[i];
            const float4 o = oe4[i];
            float4 val;
            #pragma unroll
            for (int jj = 0; jj < 4; ++jj) {
                val[jj] = c[jj] + o[jj];
                s += val[jj]; s2 += val[jj] * val[jj];
            }
            v[i] = val;
        }
    }
    s  += __shfl_xor(s, 1);  s  += __shfl_xor(s, 2);
    s2 += __shfl_xor(s2, 1); s2 += __shfl_xor(s2, 2);
    const float mean = s * (1.f / H);
    const float var  = s2 * (1.f / H) - mean * mean;
    const float rs   = rsqrtf(var + 1e-5f);
    #pragma unroll
    for (int i = 0; i < 6; ++i) {
        const float4 g = g4[i], b = b4[i];
        float4 o;
        #pragma unroll
        for (int jj = 0; jj < 4; ++jj)
            o[jj] = (v[i][jj] - mean) * rs * g[jj] + b[jj];
        oe4[i] = o;
    }
}

// ---------------------------------------------------------------------------
// agg_kernel: node-aligned segmented sum (structure proven R8-R12).
// ---------------------------------------------------------------------------
template <bool VBF, bool COBF>
__global__ __launch_bounds__(256) void agg_kernel(
    const float* __restrict__ qkv, const unsigned short* __restrict__ vbf,
    const float* __restrict__ co, const unsigned short* __restrict__ co_bf,
    const int* __restrict__ rowptr, const int* __restrict__ bucket,
    const int* __restrict__ bsrc, const int* __restrict__ dstof,
    float* __restrict__ agg, float* __restrict__ eagg)
{
    __shared__ float accA[NPA][H];
    __shared__ float accE[NPA][H];
    const int t = threadIdx.x;

    for (int i = t; i < NPA * H; i += 256) {
        ((float*)accA)[i] = 0.f;
        ((float*)accE)[i] = 0.f;
    }
    __syncthreads();

    const int n0   = blockIdx.x * NPA;
    const int nend = (n0 + NPA < N_NODES) ? (n0 + NPA) : N_NODES;
    const int P0 = rowptr[n0], P1 = rowptr[nend];
    const int count = P1 - P0;
    const int quad = t >> 2, q4 = t & 3;
    const int len  = (count + 63) >> 6;
    int p    = P0 + quad * len;
    int pend = p + len; if (pend > P1) pend = P1;

    float4 va[6], ve[6];
    #pragma unroll
    for (int i = 0; i < 6; ++i) { va[i] = (float4){0,0,0,0}; ve[i] = (float4){0,0,0,0}; }
    int cur = -1;

    for (; p < pend; ++p) {
        const int slot = dstof[p] - n0;
        if (slot != cur) {
            if (cur >= 0) {
                #pragma unroll
                for (int i = 0; i < 6; ++i)
                    #pragma unroll
                    for (int jj = 0; jj < 4; ++jj) {
                        atomicAdd(&accA[cur][24 * q4 + 4 * i + jj], va[i][jj]);
                        atomicAdd(&accE[cur][24 * q4 + 4 * i + jj], ve[i][jj]);
                    }
                #pragma unroll
                for (int i = 0; i < 6; ++i) { va[i] = (float4){0,0,0,0}; ve[i] = (float4){0,0,0,0}; }
            }
            cur = slot;
        }
        const int e  = bucket[p];
        const int sv = bsrc[p];
        if (VBF) {
            const short8* vb8 = (const short8*)(vbf + (size_t)sv * H + 24 * q4);
            #pragma unroll
            for (int j = 0; j < 3; ++j) {
                const short8 v8 = vb8[j];
                #pragma unroll
                for (int k = 0; k < 8; ++k) {
                    const int idx = 8 * j + k;
                    va[idx >> 2][idx & 3] += bf2f((unsigned short)v8[k]);
                }
            }
        } else {
            const float4* v4 = (const float4*)(qkv + (size_t)sv * QKV_N + 2 * H) + 6 * q4;
            #pragma unroll
            for (int i = 0; i < 6; ++i) {
                const float4 a = v4[i];
                #pragma unroll
                for (int jj = 0; jj < 4; ++jj) va[i][jj] += a[jj];
            }
        }
        if (COBF) {
            const short8* cb8 = (const short8*)(co_bf + (size_t)e * H + 24 * q4);
            #pragma unroll
            for (int j = 0; j < 3; ++j) {
                const short8 c8 = cb8[j];
                #pragma unroll
                for (int k = 0; k < 8; ++k) {
                    const int idx = 8 * j + k;
                    ve[idx >> 2][idx & 3] += bf2f((unsigned short)c8[k]);
                }
            }
        } else {
            const float4* c4 = (const float4*)(co + (size_t)e * H) + 6 * q4;
            #pragma unroll
            for (int i = 0; i < 6; ++i) {
                const float4 b = c4[i];
                #pragma unroll
                for (int jj = 0; jj < 4; ++jj) ve[i][jj] += b[jj];
            }
        }
    }
    if (cur >= 0) {
        #pragma unroll
        for (int i = 0; i < 6; ++i)
            #pragma unroll
            for (int jj = 0; jj < 4; ++jj) {
                atomicAdd(&accA[cur][24 * q4 + 4 * i + jj], va[i][jj]);
                atomicAdd(&accE[cur][24 * q4 + 4 * i + jj], ve[i][jj]);
            }
    }
    __syncthreads();

    const int nloc = nend - n0;
    for (int i = t; i < nloc * H; i += 256) {
        const int r = i / H, c = i - r * H;
        agg [(size_t)(n0 + r) * H + c] = accA[r][c];
        eagg[(size_t)(n0 + r) * H + c] = accE[r][c];
    }
}

// ---------------------------------------------------------------------------
// Kernel 3a (big path): node GEMVs + LN, streaming agg/eagg
// ---------------------------------------------------------------------------
__global__ __launch_bounds__(192) void node_kernel_big(
    const float* __restrict__ x,
    const float* __restrict__ agg, const float* __restrict__ eagg,
    const float* __restrict__ clw, const float* __restrict__ clb,
    const float* __restrict__ nlw, const float* __restrict__ nlb,
    const float* __restrict__ ln_g, const float* __restrict__ ln_b,
    float* __restrict__ out_h)
{
    __shared__ __align__(16) float ga[H];
    __shared__ __align__(16) float sa[H];
    __shared__ float red0[H], red1[H];
    const int t = threadIdx.x;

    float w[H];
    {
        const float* wsrc = (t < H) ? (clw + (size_t)t * H) : (nlw + (size_t)(t - H) * H);
        #pragma unroll
        for (int k4 = 0; k4 < H; k4 += 4) {
            float4 v = *(const float4*)(wsrc + k4);
            w[k4] = v.x; w[k4 + 1] = v.y; w[k4 + 2] = v.z; w[k4 + 3] = v.w;
        }
    }
    const float bias = (t < H) ? clb[t] : nlb[t - H];
    const float lg = (t >= H) ? ln_g[t - H] : 0.f;
    const float lb = (t >= H) ? ln_b[t - H] : 0.f;

    const int n0 = blockIdx.x * NPB3B;
    for (int nn = 0; nn < NPB3B; ++nn) {
        const int node = n0 + nn;
        if (node >= N_NODES) break;            // block-uniform
        __syncthreads();
        if (t < H)       ga[t]     = eagg[(size_t)node * H + t];
        else             sa[t - H] = agg[(size_t)node * H + (t - H)];
        __syncthreads();

        if (t < H) {
            float acc = bias;
            #pragma unroll
            for (int k4 = 0; k4 < H; k4 += 4) {
                float4 c = *(const float4*)(ga + k4);
                acc += c.x * w[k4] + c.y * w[k4 + 1] + c.z * w[k4 + 2] + c.w * w[k4 + 3];
            }
            sa[t] += acc;
        }
        __syncthreads();

        float val = 0.f;
        if (t >= H) {
            const int tt = t - H;
            float acc = bias;
            #pragma unroll
            for (int k4 = 0; k4 < H; k4 += 4) {
                float4 c = *(const float4*)(sa + k4);
                acc += c.x * w[k4] + c.y * w[k4 + 1] + c.z * w[k4 + 2] + c.w * w[k4 + 3];
            }
            val = acc + x[(size_t)node * H + tt];
            red0[tt] = val;
            red1[tt] = val * val;
        }
        __syncthreads();
        if (t < 32) { red0[t] += red0[t + 64]; red1[t] += red1[t + 64]; }
        __syncthreads();
        for (int s = 32; s > 0; s >>= 1) {
            if (t < s) { red0[t] += red0[t + s]; red1[t] += red1[t + s]; }
            __syncthreads();
        }
        if (t >= H) {
            const float mean = red0[0] * (1.f / H);
            const float var  = red1[0] * (1.f / H) - mean * mean;
            const float r    = rsqrtf(var + 1e-5f);
            out_h[(size_t)node * H + (t - H)] = (val - mean) * r * lg + lb;
        }
    }
}

// ---------------------------------------------------------------------------
// Kernel 3b (fallback, R7-proven): node path via CSR gather
// ---------------------------------------------------------------------------
__global__ __launch_bounds__(192) void node_kernel(
    const float* __restrict__ x, const float* __restrict__ qkv,
    const float* __restrict__ co_f32,                 // = out_e (holds raw co)
    const int* __restrict__ rowptr, const int* __restrict__ bucket,
    const int* __restrict__ bsrc,
    const float* __restrict__ clw, const float* __restrict__ clb,
    const float* __restrict__ nlw, const float* __restrict__ nlb,
    const float* __restrict__ ln_g, const float* __restrict__ ln_b,
    float* __restrict__ out_h)
{
    __shared__ __align__(16) float ga[H];
    __shared__ __align__(16) float sa[H];
    __shared__ float pa2[192], pe2[192];
    __shared__ float red0[H], red1[H];
    const int t = threadIdx.x;
    const int col = (t < H) ? t : (t - H);
    const int par = (t < H) ? 0 : 1;

    float w[H];
    {
        const float* wsrc = (t < H) ? (clw + (size_t)t * H) : (nlw + (size_t)(t - H) * H);
        #pragma unroll
        for (int k4 = 0; k4 < H; k4 += 4) {
            float4 v = *(const float4*)(wsrc + k4);
            w[k4] = v.x; w[k4 + 1] = v.y; w[k4 + 2] = v.z; w[k4 + 3] = v.w;
        }
    }
    const float bias = (t < H) ? clb[t] : nlb[t - H];
    const float lg = (t >= H) ? ln_g[t - H] : 0.f;
    const float lb = (t >= H) ? ln_b[t - H] : 0.f;

    const int n0 = blockIdx.x * NPB3;
    for (int nn = 0; nn < NPB3; ++nn) {
        const int node = n0 + nn;
        if (node >= N_NODES) break;            // block-uniform
        const int r0 = rowptr[node], r1 = rowptr[node + 1];

        float pa = 0.f, pe = 0.f;
        for (int j = r0 + par; j < r1; j += 2) {
            const int ee = bucket[j];
            const int sv = bsrc[j];
            pa += qkv[(size_t)sv * QKV_N + 2 * H + col];
            pe += co_f32[(size_t)ee * H + col];
        }
        __syncthreads();
        pa2[t] = pa; pe2[t] = pe;
        __syncthreads();
        if (t < H) ga[t]      = pe2[t] + pe2[t + H];
        else       sa[t - H]  = pa2[t - H] + pa2[t];
        __syncthreads();

        if (t < H) {
            float acc = bias;
            #pragma unroll
            for (int k4 = 0; k4 < H; k4 += 4) {
                float4 c = *(const float4*)(ga + k4);
                acc += c.x * w[k4] + c.y * w[k4 + 1] + c.z * w[k4 + 2] + c.w * w[k4 + 3];
            }
            sa[t] += acc;
        }
        __syncthreads();

        float val = 0.f;
        if (t >= H) {
            const int tt = t - H;
            float acc = bias;
            #pragma unroll
            for (int k4 = 0; k4 < H; k4 += 4) {
                float4 c = *(const float4*)(sa + k4);
                acc += c.x * w[k4] + c.y * w[k4 + 1] + c.z * w[k4 + 2] + c.w * w[k4 + 3];
            }
            val = acc + x[(size_t)node * H + tt];
            red0[tt] = val;
            red1[tt] = val * val;
        }
        __syncthreads();
        if (t < 32) { red0[t] += red0[t + 64]; red1[t] += red1[t + 64]; }
        __syncthreads();
        for (int s = 32; s > 0; s >>= 1) {
            if (t < s) { red0[t] += red0[t + s]; red1[t] += red1[t + s]; }
            __syncthreads();
        }
        if (t >= H) {
            const float mean = red0[0] * (1.f / H);
            const float var  = red1[0] * (1.f / H) - mean * mean;
            const float r    = rsqrtf(var + 1e-5f);
            out_h[(size_t)node * H + (t - H)] = (val - mean) * r * lg + lb;
        }
    }
}

// ---------------------------------------------------------------------------
extern "C" void kernel_launch(void* const* d_in, const int* in_sizes, int n_in,
                              void* d_out, int out_size, void* d_ws, size_t ws_size,
                              hipStream_t stream) {
    const float* x      = (const float*)d_in[0];
    const float* conn   = (const float*)d_in[1];
    const int*   eidx   = (const int*)  d_in[2];
    const float* qkv_w  = (const float*)d_in[3];
    const float* qkv_b  = (const float*)d_in[4];
    const float* e_w    = (const float*)d_in[5];
    const float* e_b    = (const float*)d_in[6];
    const float* clw    = (const float*)d_in[7];
    const float* clb    = (const float*)d_in[8];
    const float* nlw    = (const float*)d_in[9];
    const float* nlb    = (const float*)d_in[10];
    const float* ln_h_g = (const float*)d_in[11];
    const float* ln_h_b = (const float*)d_in[12];
    const float* ln_e_g = (const float*)d_in[13];
    const float* ln_e_b = (const float*)d_in[14];

    float* out_h = (float*)d_out;                        // 50000*96
    float* out_e = out_h + (size_t)N_NODES * H;          // 800000*96

    // ---- ws: qkv | rowptr | hist | bucket | bsrc | dstof | agg | eagg | vbf | cobf
    char* base = (char*)d_ws;
    float* qkv = (float*)base;
    size_t off = (size_t)N_NODES * QKV_N * sizeof(float);        // 57.6 MB
    int* rowptr = (int*)(base + off); off += (size_t)(N_NODES + 1) * 4;
    int* hist   = (int*)(base + off); off += (size_t)N_NODES * 4;
    int* bucket = (int*)(base + off); off += (size_t)N_EDGES * 4;
    int* bsrc   = (int*)(base + off); off += (size_t)N_EDGES * 4;        // 64.4 MB
    int*   dstof = (int*)(base + off);  off += (size_t)N_EDGES * 4;      // 67.6
    float* agg   = (float*)(base + off); off += (size_t)N_NODES * H * 4;
    float* eagg  = (float*)(base + off); off += (size_t)N_NODES * H * 4; // 106 MB
    unsigned short* vbf = (unsigned short*)(base + off);
    off += (size_t)N_NODES * H * 2;                                      // 115.6 MB
    const size_t need_B = off;
    unsigned short* cobf = (unsigned short*)(base + off);
    off += (size_t)N_EDGES * H * 2;                                      // 269.2 MB
    const size_t need_A = off;

    const bool A = ws_size >= need_A;
    const bool B = !A && ws_size >= need_B;

    hipMemsetAsync(hist, 0, (size_t)N_NODES * 4, stream);

    qkv_kernel    <<<(N_NODES + NPB1 - 1) / NPB1, QKV_N, 0, stream>>>(
        x, qkv_w, qkv_b, qkv, (A || B) ? vbf : nullptr);
    hist_kernel   <<<(N_EDGES + 255) / 256, 256, 0, stream>>>(eidx, hist);
    scan_kernel   <<<1, 1024, 0, stream>>>(hist, rowptr);
    scatter_kernel<<<(N_EDGES + 255) / 256, 256, 0, stream>>>(eidx, hist, bucket, bsrc,
                                                              (A || B) ? dstof : nullptr);

    if (A) {
        edge_kernel<true><<<N_EDGES / TILE_E, 256, 0, stream>>>(
            conn, eidx, qkv, e_w, e_b, cobf, out_e);
        agg_kernel<true, true><<<(N_NODES + NPA - 1) / NPA, 256, 0, stream>>>(
            qkv, vbf, out_e, cobf, rowptr, bucket, bsrc, dstof, agg, eagg);
        node_kernel_big<<<(N_NODES + NPB3B - 1) / NPB3B, 192, 0, stream>>>(
            x, agg, eagg, clw, clb, nlw, nlb, ln_h_g, ln_h_b, out_h);
        eln_kernel<true><<<(N_EDGES * 4) / 256, 256, 0, stream>>>(
            conn, cobf, ln_e_g, ln_e_b, out_e);
    } else if (B) {
        edge_kernel<false><<<N_EDGES / TILE_E, 256, 0, stream>>>(
            conn, eidx, qkv, e_w, e_b, nullptr, out_e);
        agg_kernel<true, false><<<(N_NODES + NPA - 1) / NPA, 256, 0, stream>>>(
            qkv, vbf, out_e, nullptr, rowptr, bucket, bsrc, dstof, agg, eagg);
        node_kernel_big<<<(N_NODES + NPB3B - 1) / NPB3B, 192, 0, stream>>>(
            x, agg, eagg, clw, clb, nlw, nlb, ln_h_g, ln_h_b, out_h);
        eln_kernel<false><<<(N_EDGES * 4) / 256, 256, 0, stream>>>(
            conn, nullptr, ln_e_g, ln_e_b, out_e);
    } else {
        edge_kernel<false><<<N_EDGES / TILE_E, 256, 0, stream>>>(
            conn, eidx, qkv, e_w, e_b, nullptr, out_e);
        node_kernel<<<(N_NODES + NPB3 - 1) / NPB3, 192, 0, stream>>>(
            x, qkv, out_e, rowptr, bucket, bsrc,
            clw, clb, nlw, nlb, ln_h_g, ln_h_b, out_h);
        eln_kernel<false><<<(N_EDGES * 4) / 256, 256, 0, stream>>>(
            conn, nullptr, ln_e_g, ln_e_b, out_e);
    }
}

// Round 14
// 1277.232 us; speedup vs baseline: 1.0169x; 1.0169x over previous
//
#include <hip/hip_runtime.h>
#include <math.h>

#define N_NODES 50000
#define N_EDGES 800000
#define H 96
#define QKV_N 288

#define NPB1 32   // nodes per block, qkv kernel
#define NPB3 4    // nodes per block, node kernel (gather fallback, R7-proven)
#define NPB3B 8   // nodes per block, node kernel (big path, streaming)
#define NPA 32    // nodes per agg block

typedef __attribute__((ext_vector_type(8))) short short8;   // 8 bf16 = 4 VGPRs
typedef __attribute__((ext_vector_type(4))) float f32x4;    // MFMA accumulator

// float -> bf16 (RNE) — used for storage roundings (vbf, cobf).
__device__ __forceinline__ short f2bf(float f) {
    union { float f; unsigned u; } v; v.f = f;
    unsigned r = v.u + 0x7FFFu + ((v.u >> 16) & 1u);
    return (short)(r >> 16);
}
__device__ __forceinline__ float bf2f(unsigned short h) {
    union { unsigned u; float f; } v; v.u = ((unsigned)h) << 16;
    return v.f;
}

// TRUNCATION hi/lo split (R12-proven): hi = top 16 bits (exact); residual is
// exactly representable; lo = trunc-bf16(residual). Dropped err <= 2^-16|f|.
__device__ __forceinline__ void ld_frag_split(const float* __restrict__ p,
                                              short8& hi, short8& lo) {
    float4 a = *(const float4*)p;
    float4 b = *(const float4*)(p + 4);
    float f[8] = {a.x, a.y, a.z, a.w, b.x, b.y, b.z, b.w};
    #pragma unroll
    for (int j = 0; j < 8; ++j) {
        union { float f; unsigned u; } v; v.f = f[j];
        hi[j] = (short)(v.u >> 16);
        union { unsigned u; float f; } h; h.u = v.u & 0xFFFF0000u;
        union { float f; unsigned u; } l; l.f = f[j] - h.f;
        lo[j] = (short)(l.u >> 16);
    }
}

// ---------------------------------------------------------------------------
// Kernel 1: qkv[n, t] = dot(x[n, :], qkv_w[t, :]) + qkv_b[t]   (t < 288)
// Also emits V as bf16 (vbf) for the L2-resident agg gather.
// ---------------------------------------------------------------------------
__global__ __launch_bounds__(QKV_N) void qkv_kernel(
    const float* __restrict__ x, const float* __restrict__ qw,
    const float* __restrict__ qb, float* __restrict__ qkv,
    unsigned short* __restrict__ vbf)
{
    __shared__ __align__(16) float xs[H];
    const int t = threadIdx.x;

    float w[H];
    #pragma unroll
    for (int k4 = 0; k4 < H; k4 += 4) {
        float4 v = *(const float4*)(qw + (size_t)t * H + k4);
        w[k4] = v.x; w[k4 + 1] = v.y; w[k4 + 2] = v.z; w[k4 + 3] = v.w;
    }
    const float bias = qb[t];

    const int n0 = blockIdx.x * NPB1;
    for (int nn = 0; nn < NPB1; ++nn) {
        const int node = n0 + nn;
        if (node >= N_NODES) break;          // block-uniform
        __syncthreads();
        if (t < H) xs[t] = x[(size_t)node * H + t];
        __syncthreads();
        float acc = bias;
        #pragma unroll
        for (int k4 = 0; k4 < H; k4 += 4) {
            float4 c = *(const float4*)(xs + k4);
            acc += c.x * w[k4] + c.y * w[k4 + 1] + c.z * w[k4 + 2] + c.w * w[k4 + 3];
        }
        qkv[(size_t)node * QKV_N + t] = acc;
        if (vbf && t >= 2 * H)
            vbf[(size_t)node * H + (t - 2 * H)] = (unsigned short)f2bf(acc);
    }
}

// ---------------------------------------------------------------------------
// CSR build: histogram -> scan -> scatter   (proven R4-R12)
// ---------------------------------------------------------------------------
__global__ __launch_bounds__(256) void hist_kernel(const int* __restrict__ eidx,
                                                   int* __restrict__ hist) {
    const int e = blockIdx.x * 256 + threadIdx.x;
    if (e < N_EDGES) atomicAdd(&hist[eidx[e]], 1);
}

#define SCAN_CH 49   // 1024*49 = 50176 >= 50000
__global__ __launch_bounds__(1024) void scan_kernel(int* __restrict__ hist,
                                                    int* __restrict__ rowptr) {
    __shared__ int sums[1024];
    const int t = threadIdx.x;
    const int st = t * SCAN_CH;
    int loc = 0;
    for (int k = 0; k < SCAN_CH; ++k) {
        const int i = st + k;
        if (i < N_NODES) loc += hist[i];
    }
    sums[t] = loc;
    __syncthreads();
    for (int off = 1; off < 1024; off <<= 1) {
        int add = (t >= off) ? sums[t - off] : 0;
        __syncthreads();
        sums[t] += add;
        __syncthreads();
    }
    int run = sums[t] - loc;     // exclusive prefix of this thread's chunk
    for (int k = 0; k < SCAN_CH; ++k) {
        const int i = st + k;
        if (i < N_NODES) {
            const int v = hist[i];
            rowptr[i] = run;
            hist[i]   = run;     // hist becomes the scatter cursor
            run += v;
        }
    }
    if (t == 1023) rowptr[N_NODES] = run;   // = N_EDGES
}

__global__ __launch_bounds__(256) void scatter_kernel(const int* __restrict__ eidx,
                                                      int* __restrict__ cursor,
                                                      int* __restrict__ bucket,
                                                      int* __restrict__ bsrc,
                                                      int* __restrict__ dstof) {
    const int e = blockIdx.x * 256 + threadIdx.x;
    if (e < N_EDGES) {
        const int dst = eidx[e];
        const int src = eidx[N_EDGES + e];
        const int pos = atomicAdd(&cursor[dst], 1);
        bucket[pos] = e;
        bsrc[pos]   = src;
        if (dstof) dstof[pos] = dst;
    }
}

// ---------------------------------------------------------------------------
// Kernel 2 (MFMA, bf16x3 trunc-split, fp32 eh tile — R12-verbatim except):
// R14's single change: Q/K rows are PREFETCHED into registers at kernel
// start (addresses depend only on eidx), so their ~400-900 cy random-read
// latency is hidden under the B-frag conversion + MFMA + LDS staging instead
// of stalling the post-barrier pointwise phase.
// NO LN fusion (abandoned: R4/R10/R11). NO bf16 eh tile (abandoned: R13).
// ---------------------------------------------------------------------------
#define TILE_E 64
#define EH_LD 196

template <bool COBF>
__global__ __launch_bounds__(256) void edge_kernel(
    const float* __restrict__ conn, const int* __restrict__ eidx,
    const float* __restrict__ qkv,
    const float* __restrict__ ew, const float* __restrict__ eb,
    unsigned short* __restrict__ co_bf, float* __restrict__ out_e)
{
    __shared__ __align__(16) float eh[TILE_E * EH_LD];   // 64 x 196 f32 = 50176 B

    const int t    = threadIdx.x;
    const int wave = t >> 6;
    const int lane = t & 63;
    const int lr   = lane & 15;
    const int lg16 = lane >> 4;

    const int e0 = blockIdx.x * TILE_E;

    // ---- R14: early Q/K prefetch (independent of MFMA work) ----
    const int e_loc = t >> 2;
    const int q4    = t & 3;
    const int e     = e0 + e_loc;
    const int dst   = eidx[e];
    const int src   = eidx[N_EDGES + e];
    const float4* qQ4 = (const float4*)(qkv + (size_t)dst * QKV_N) + 6 * q4;
    const float4* qK4 = (const float4*)(qkv + (size_t)src * QKV_N + H) + 6 * q4;
    float4 qv[6], kv[6];
    #pragma unroll
    for (int i = 0; i < 6; ++i) { qv[i] = qQ4[i]; kv[i] = qK4[i]; }

    // ---- B fragments (hi+lo): e_w rows are B^T rows ----
    short8 bwh[3][3], bwl[3][3];
    #pragma unroll
    for (int f = 0; f < 3; ++f) {
        const int tcol = 16 * (3 * wave + f) + lr;
        #pragma unroll
        for (int kc = 0; kc < 3; ++kc)
            ld_frag_split(ew + (size_t)tcol * H + 32 * kc + 8 * lg16,
                          bwh[f][kc], bwl[f][kc]);
    }

    f32x4 acc[4][3];
    #pragma unroll
    for (int mt = 0; mt < 4; ++mt)
        #pragma unroll
        for (int f = 0; f < 3; ++f)
            acc[mt][f] = (f32x4){0.f, 0.f, 0.f, 0.f};

    #pragma unroll
    for (int mt = 0; mt < 4; ++mt) {
        const int erow = e0 + 16 * mt + lr;
        short8 ah[3], al[3];
        #pragma unroll
        for (int kc = 0; kc < 3; ++kc)
            ld_frag_split(conn + (size_t)erow * H + 32 * kc + 8 * lg16,
                          ah[kc], al[kc]);
        #pragma unroll
        for (int f = 0; f < 3; ++f) {
            #pragma unroll
            for (int kc = 0; kc < 3; ++kc) {
                acc[mt][f] = __builtin_amdgcn_mfma_f32_16x16x32_bf16(
                                 ah[kc], bwl[f][kc], acc[mt][f], 0, 0, 0);
                acc[mt][f] = __builtin_amdgcn_mfma_f32_16x16x32_bf16(
                                 al[kc], bwh[f][kc], acc[mt][f], 0, 0, 0);
                acc[mt][f] = __builtin_amdgcn_mfma_f32_16x16x32_bf16(
                                 ah[kc], bwh[f][kc], acc[mt][f], 0, 0, 0);
            }
        }
    }

    // ---- write Eh (+bias) to LDS (fp32, R12-verbatim) ----
    #pragma unroll
    for (int mt = 0; mt < 4; ++mt) {
        #pragma unroll
        for (int f = 0; f < 3; ++f) {
            const int col = 16 * (3 * wave + f) + lr;
            const float bias = eb[col];
            #pragma unroll
            for (int r = 0; r < 4; ++r) {
                const int row = 16 * mt + 4 * lg16 + r;
                eh[row * EH_LD + col] = acc[mt][f][r] + bias;
            }
        }
    }
    __syncthreads();

    // ---- pointwise: lane q4 owns cols [24*q4, 24*q4+24); Q/K from regs ----
    float4*          oe4 = (float4*)(out_e + (size_t)e * H) + 6 * q4;
    unsigned short*  cb  = COBF ? (co_bf + (size_t)e * H + 24 * q4) : nullptr;
    const float*  ehr = &eh[e_loc * EH_LD + 24 * q4];

    #pragma unroll
    for (int i = 0; i < 6; ++i) {
        const float4 q  = qv[i];
        const float4 k  = kv[i];
        const float4 w4 = *(const float4*)(ehr + 4 * i);
        const float4 b4 = *(const float4*)(ehr + 4 * i + H);
        float4 co4;
        #pragma unroll
        for (int jj = 0; jj < 4; ++jj) {
            const float c1 = (q[jj] + k[jj]) * w4[jj];
            const float c2 = copysignf(sqrtf(fabsf(c1)), c1);
            co4[jj] = fmaxf(c2 + b4[jj], 0.f);
        }
        if (COBF) {
            ushort4 pk;
            pk.x = (unsigned short)f2bf(co4[0]);
            pk.y = (unsigned short)f2bf(co4[1]);
            pk.z = (unsigned short)f2bf(co4[2]);
            pk.w = (unsigned short)f2bf(co4[3]);
            *(ushort4*)(cb + 4 * i) = pk;
        } else {
            oe4[i] = co4;
        }
    }
}

// ---------------------------------------------------------------------------
// eln: out_e = LN(conn + co). COBF: co from bf16 co_bf; else in-place fp32.
// (R9/R12-verbatim, proven.)
// ---------------------------------------------------------------------------
template <bool COBF>
__global__ __launch_bounds__(256) void eln_kernel(
    const float* __restrict__ conn, const unsigned short* __restrict__ co_bf,
    const float* __restrict__ ln_g, const float* __restrict__ ln_b,
    float* __restrict__ out_e)
{
    const int tt   = blockIdx.x * 256 + threadIdx.x;
    const size_t e = (size_t)(tt >> 2);
    const int q4   = tt & 3;
    const float4* cn4 = (const float4*)(conn + e * H) + 6 * q4;
    float4*       oe4 = (float4*)(out_e + e * H) + 6 * q4;
    const float4* g4  = (const float4*)ln_g + 6 * q4;
    const float4* b4  = (const float4*)ln_b + 6 * q4;

    float4 v[6];
    float s = 0.f, s2 = 0.f;
    if (COBF) {
        const short8* cb8 = (const short8*)(co_bf + e * H + 24 * q4);
        #pragma unroll
        for (int j = 0; j < 3; ++j) {
            const short8 c8 = cb8[j];
            const float4 cA = cn4[2 * j];
            const float4 cB = cn4[2 * j + 1];
            #pragma unroll
            for (int k = 0; k < 4; ++k) {
                const float a = cA[k] + bf2f((unsigned short)c8[k]);
                const float b = cB[k] + bf2f((unsigned short)c8[4 + k]);
                v[2 * j][k] = a; v[2 * j + 1][k] = b;
                s += a + b; s2 += a * a + b * b;
            }
        }
    } else {
        #pragma unroll
        for (int i = 0; i < 6; ++i) {
            const float4 c = cn4[i];
            const float4 o = oe4[i];
            float4 val;
            #pragma unroll
            for (int jj = 0; jj < 4; ++jj) {
                val[jj] = c[jj] + o[jj];
                s += val[jj]; s2 += val[jj] * val[jj];
            }
            v[i] = val;
        }
    }
    s  += __shfl_xor(s, 1);  s  += __shfl_xor(s, 2);
    s2 += __shfl_xor(s2, 1); s2 += __shfl_xor(s2, 2);
    const float mean = s * (1.f / H);
    const float var  = s2 * (1.f / H) - mean * mean;
    const float rs   = rsqrtf(var + 1e-5f);
    #pragma unroll
    for (int i = 0; i < 6; ++i) {
        const float4 g = g4[i], b = b4[i];
        float4 o;
        #pragma unroll
        for (int jj = 0; jj < 4; ++jj)
            o[jj] = (v[i][jj] - mean) * rs * g[jj] + b[jj];
        oe4[i] = o;
    }
}

// ---------------------------------------------------------------------------
// agg_kernel: node-aligned segmented sum (structure proven R8-R12).
// ---------------------------------------------------------------------------
template <bool VBF, bool COBF>
__global__ __launch_bounds__(256) void agg_kernel(
    const float* __restrict__ qkv, const unsigned short* __restrict__ vbf,
    const float* __restrict__ co, const unsigned short* __restrict__ co_bf,
    const int* __restrict__ rowptr, const int* __restrict__ bucket,
    const int* __restrict__ bsrc, const int* __restrict__ dstof,
    float* __restrict__ agg, float* __restrict__ eagg)
{
    __shared__ float accA[NPA][H];
    __shared__ float accE[NPA][H];
    const int t = threadIdx.x;

    for (int i = t; i < NPA * H; i += 256) {
        ((float*)accA)[i] = 0.f;
        ((float*)accE)[i] = 0.f;
    }
    __syncthreads();

    const int n0   = blockIdx.x * NPA;
    const int nend = (n0 + NPA < N_NODES) ? (n0 + NPA) : N_NODES;
    const int P0 = rowptr[n0], P1 = rowptr[nend];
    const int count = P1 - P0;
    const int quad = t >> 2, q4 = t & 3;
    const int len  = (count + 63) >> 6;
    int p    = P0 + quad * len;
    int pend = p + len; if (pend > P1) pend = P1;

    float4 va[6], ve[6];
    #pragma unroll
    for (int i = 0; i < 6; ++i) { va[i] = (float4){0,0,0,0}; ve[i] = (float4){0,0,0,0}; }
    int cur = -1;

    for (; p < pend; ++p) {
        const int slot = dstof[p] - n0;
        if (slot != cur) {
            if (cur >= 0) {
                #pragma unroll
                for (int i = 0; i < 6; ++i)
                    #pragma unroll
                    for (int jj = 0; jj < 4; ++jj) {
                        atomicAdd(&accA[cur][24 * q4 + 4 * i + jj], va[i][jj]);
                        atomicAdd(&accE[cur][24 * q4 + 4 * i + jj], ve[i][jj]);
                    }
                #pragma unroll
                for (int i = 0; i < 6; ++i) { va[i] = (float4){0,0,0,0}; ve[i] = (float4){0,0,0,0}; }
            }
            cur = slot;
        }
        const int e  = bucket[p];
        const int sv = bsrc[p];
        if (VBF) {
            const short8* vb8 = (const short8*)(vbf + (size_t)sv * H + 24 * q4);
            #pragma unroll
            for (int j = 0; j < 3; ++j) {
                const short8 v8 = vb8[j];
                #pragma unroll
                for (int k = 0; k < 8; ++k) {
                    const int idx = 8 * j + k;
                    va[idx >> 2][idx & 3] += bf2f((unsigned short)v8[k]);
                }
            }
        } else {
            const float4* v4 = (const float4*)(qkv + (size_t)sv * QKV_N + 2 * H) + 6 * q4;
            #pragma unroll
            for (int i = 0; i < 6; ++i) {
                const float4 a = v4[i];
                #pragma unroll
                for (int jj = 0; jj < 4; ++jj) va[i][jj] += a[jj];
            }
        }
        if (COBF) {
            const short8* cb8 = (const short8*)(co_bf + (size_t)e * H + 24 * q4);
            #pragma unroll
            for (int j = 0; j < 3; ++j) {
                const short8 c8 = cb8[j];
                #pragma unroll
                for (int k = 0; k < 8; ++k) {
                    const int idx = 8 * j + k;
                    ve[idx >> 2][idx & 3] += bf2f((unsigned short)c8[k]);
                }
            }
        } else {
            const float4* c4 = (const float4*)(co + (size_t)e * H) + 6 * q4;
            #pragma unroll
            for (int i = 0; i < 6; ++i) {
                const float4 b = c4[i];
                #pragma unroll
                for (int jj = 0; jj < 4; ++jj) ve[i][jj] += b[jj];
            }
        }
    }
    if (cur >= 0) {
        #pragma unroll
        for (int i = 0; i < 6; ++i)
            #pragma unroll
            for (int jj = 0; jj < 4; ++jj) {
                atomicAdd(&accA[cur][24 * q4 + 4 * i + jj], va[i][jj]);
                atomicAdd(&accE[cur][24 * q4 + 4 * i + jj], ve[i][jj]);
            }
    }
    __syncthreads();

    const int nloc = nend - n0;
    for (int i = t; i < nloc * H; i += 256) {
        const int r = i / H, c = i - r * H;
        agg [(size_t)(n0 + r) * H + c] = accA[r][c];
        eagg[(size_t)(n0 + r) * H + c] = accE[r][c];
    }
}

// ---------------------------------------------------------------------------
// Kernel 3a (big path): node GEMVs + LN, streaming agg/eagg
// ---------------------------------------------------------------------------
__global__ __launch_bounds__(192) void node_kernel_big(
    const float* __restrict__ x,
    const float* __restrict__ agg, const float* __restrict__ eagg,
    const float* __restrict__ clw, const float* __restrict__ clb,
    const float* __restrict__ nlw, const float* __restrict__ nlb,
    const float* __restrict__ ln_g, const float* __restrict__ ln_b,
    float* __restrict__ out_h)
{
    __shared__ __align__(16) float ga[H];
    __shared__ __align__(16) float sa[H];
    __shared__ float red0[H], red1[H];
    const int t = threadIdx.x;

    float w[H];
    {
        const float* wsrc = (t < H) ? (clw + (size_t)t * H) : (nlw + (size_t)(t - H) * H);
        #pragma unroll
        for (int k4 = 0; k4 < H; k4 += 4) {
            float4 v = *(const float4*)(wsrc + k4);
            w[k4] = v.x; w[k4 + 1] = v.y; w[k4 + 2] = v.z; w[k4 + 3] = v.w;
        }
    }
    const float bias = (t < H) ? clb[t] : nlb[t - H];
    const float lg = (t >= H) ? ln_g[t - H] : 0.f;
    const float lb = (t >= H) ? ln_b[t - H] : 0.f;

    const int n0 = blockIdx.x * NPB3B;
    for (int nn = 0; nn < NPB3B; ++nn) {
        const int node = n0 + nn;
        if (node >= N_NODES) break;            // block-uniform
        __syncthreads();
        if (t < H)       ga[t]     = eagg[(size_t)node * H + t];
        else             sa[t - H] = agg[(size_t)node * H + (t - H)];
        __syncthreads();

        if (t < H) {
            float acc = bias;
            #pragma unroll
            for (int k4 = 0; k4 < H; k4 += 4) {
                float4 c = *(const float4*)(ga + k4);
                acc += c.x * w[k4] + c.y * w[k4 + 1] + c.z * w[k4 + 2] + c.w * w[k4 + 3];
            }
            sa[t] += acc;
        }
        __syncthreads();

        float val = 0.f;
        if (t >= H) {
            const int tt = t - H;
            float acc = bias;
            #pragma unroll
            for (int k4 = 0; k4 < H; k4 += 4) {
                float4 c = *(const float4*)(sa + k4);
                acc += c.x * w[k4] + c.y * w[k4 + 1] + c.z * w[k4 + 2] + c.w * w[k4 + 3];
            }
            val = acc + x[(size_t)node * H + tt];
            red0[tt] = val;
            red1[tt] = val * val;
        }
        __syncthreads();
        if (t < 32) { red0[t] += red0[t + 64]; red1[t] += red1[t + 64]; }
        __syncthreads();
        for (int s = 32; s > 0; s >>= 1) {
            if (t < s) { red0[t] += red0[t + s]; red1[t] += red1[t + s]; }
            __syncthreads();
        }
        if (t >= H) {
            const float mean = red0[0] * (1.f / H);
            const float var  = red1[0] * (1.f / H) - mean * mean;
            const float r    = rsqrtf(var + 1e-5f);
            out_h[(size_t)node * H + (t - H)] = (val - mean) * r * lg + lb;
        }
    }
}

// ---------------------------------------------------------------------------
// Kernel 3b (fallback, R7-proven): node path via CSR gather
// ---------------------------------------------------------------------------
__global__ __launch_bounds__(192) void node_kernel(
    const float* __restrict__ x, const float* __restrict__ qkv,
    const float* __restrict__ co_f32,                 // = out_e (holds raw co)
    const int* __restrict__ rowptr, const int* __restrict__ bucket,
    const int* __restrict__ bsrc,
    const float* __restrict__ clw, const float* __restrict__ clb,
    const float* __restrict__ nlw, const float* __restrict__ nlb,
    const float* __restrict__ ln_g, const float* __restrict__ ln_b,
    float* __restrict__ out_h)
{
    __shared__ __align__(16) float ga[H];
    __shared__ __align__(16) float sa[H];
    __shared__ float pa2[192], pe2[192];
    __shared__ float red0[H], red1[H];
    const int t = threadIdx.x;
    const int col = (t < H) ? t : (t - H);
    const int par = (t < H) ? 0 : 1;

    float w[H];
    {
        const float* wsrc = (t < H) ? (clw + (size_t)t * H) : (nlw + (size_t)(t - H) * H);
        #pragma unroll
        for (int k4 = 0; k4 < H; k4 += 4) {
            float4 v = *(const float4*)(wsrc + k4);
            w[k4] = v.x; w[k4 + 1] = v.y; w[k4 + 2] = v.z; w[k4 + 3] = v.w;
        }
    }
    const float bias = (t < H) ? clb[t] : nlb[t - H];
    const float lg = (t >= H) ? ln_g[t - H] : 0.f;
    const float lb = (t >= H) ? ln_b[t - H] : 0.f;

    const int n0 = blockIdx.x * NPB3;
    for (int nn = 0; nn < NPB3; ++nn) {
        const int node = n0 + nn;
        if (node >= N_NODES) break;            // block-uniform
        const int r0 = rowptr[node], r1 = rowptr[node + 1];

        float pa = 0.f, pe = 0.f;
        for (int j = r0 + par; j < r1; j += 2) {
            const int ee = bucket[j];
            const int sv = bsrc[j];
            pa += qkv[(size_t)sv * QKV_N + 2 * H + col];
            pe += co_f32[(size_t)ee * H + col];
        }
        __syncthreads();
        pa2[t] = pa; pe2[t] = pe;
        __syncthreads();
        if (t < H) ga[t]      = pe2[t] + pe2[t + H];
        else       sa[t - H]  = pa2[t - H] + pa2[t];
        __syncthreads();

        if (t < H) {
            float acc = bias;
            #pragma unroll
            for (int k4 = 0; k4 < H; k4 += 4) {
                float4 c = *(const float4*)(ga + k4);
                acc += c.x * w[k4] + c.y * w[k4 + 1] + c.z * w[k4 + 2] + c.w * w[k4 + 3];
            }
            sa[t] += acc;
        }
        __syncthreads();

        float val = 0.f;
        if (t >= H) {
            const int tt = t - H;
            float acc = bias;
            #pragma unroll
            for (int k4 = 0; k4 < H; k4 += 4) {
                float4 c = *(const float4*)(sa + k4);
                acc += c.x * w[k4] + c.y * w[k4 + 1] + c.z * w[k4 + 2] + c.w * w[k4 + 3];
            }
            val = acc + x[(size_t)node * H + tt];
            red0[tt] = val;
            red1[tt] = val * val;
        }
        __syncthreads();
        if (t < 32) { red0[t] += red0[t + 64]; red1[t] += red1[t + 64]; }
        __syncthreads();
        for (int s = 32; s > 0; s >>= 1) {
            if (t < s) { red0[t] += red0[t + s]; red1[t] += red1[t + s]; }
            __syncthreads();
        }
        if (t >= H) {
            const float mean = red0[0] * (1.f / H);
            const float var  = red1[0] * (1.f / H) - mean * mean;
            const float r    = rsqrtf(var + 1e-5f);
            out_h[(size_t)node * H + (t - H)] = (val - mean) * r * lg + lb;
        }
    }
}

// ---------------------------------------------------------------------------
extern "C" void kernel_launch(void* const* d_in, const int* in_sizes, int n_in,
                              void* d_out, int out_size, void* d_ws, size_t ws_size,
                              hipStream_t stream) {
    const float* x      = (const float*)d_in[0];
    const float* conn   = (const float*)d_in[1];
    const int*   eidx   = (const int*)  d_in[2];
    const float* qkv_w  = (const float*)d_in[3];
    const float* qkv_b  = (const float*)d_in[4];
    const float* e_w    = (const float*)d_in[5];
    const float* e_b    = (const float*)d_in[6];
    const float* clw    = (const float*)d_in[7];
    const float* clb    = (const float*)d_in[8];
    const float* nlw    = (const float*)d_in[9];
    const float* nlb    = (const float*)d_in[10];
    const float* ln_h_g = (const float*)d_in[11];
    const float* ln_h_b = (const float*)d_in[12];
    const float* ln_e_g = (const float*)d_in[13];
    const float* ln_e_b = (const float*)d_in[14];

    float* out_h = (float*)d_out;                        // 50000*96
    float* out_e = out_h + (size_t)N_NODES * H;          // 800000*96

    // ---- ws: qkv | rowptr | hist | bucket | bsrc | dstof | agg | eagg | vbf | cobf
    char* base = (char*)d_ws;
    float* qkv = (float*)base;
    size_t off = (size_t)N_NODES * QKV_N * sizeof(float);        // 57.6 MB
    int* rowptr = (int*)(base + off); off += (size_t)(N_NODES + 1) * 4;
    int* hist   = (int*)(base + off); off += (size_t)N_NODES * 4;
    int* bucket = (int*)(base + off); off += (size_t)N_EDGES * 4;
    int* bsrc   = (int*)(base + off); off += (size_t)N_EDGES * 4;        // 64.4 MB
    int*   dstof = (int*)(base + off);  off += (size_t)N_EDGES * 4;      // 67.6
    float* agg   = (float*)(base + off); off += (size_t)N_NODES * H * 4;
    float* eagg  = (float*)(base + off); off += (size_t)N_NODES * H * 4; // 106 MB
    unsigned short* vbf = (unsigned short*)(base + off);
    off += (size_t)N_NODES * H * 2;                                      // 115.6 MB
    const size_t need_B = off;
    unsigned short* cobf = (unsigned short*)(base + off);
    off += (size_t)N_EDGES * H * 2;                                      // 269.2 MB
    const size_t need_A = off;

    const bool A = ws_size >= need_A;
    const bool B = !A && ws_size >= need_B;

    hipMemsetAsync(hist, 0, (size_t)N_NODES * 4, stream);

    qkv_kernel    <<<(N_NODES + NPB1 - 1) / NPB1, QKV_N, 0, stream>>>(
        x, qkv_w, qkv_b, qkv, (A || B) ? vbf : nullptr);
    hist_kernel   <<<(N_EDGES + 255) / 256, 256, 0, stream>>>(eidx, hist);
    scan_kernel   <<<1, 1024, 0, stream>>>(hist, rowptr);
    scatter_kernel<<<(N_EDGES + 255) / 256, 256, 0, stream>>>(eidx, hist, bucket, bsrc,
                                                              (A || B) ? dstof : nullptr);

    if (A) {
        edge_kernel<true><<<N_EDGES / TILE_E, 256, 0, stream>>>(
            conn, eidx, qkv, e_w, e_b, cobf, out_e);
        agg_kernel<true, true><<<(N_NODES + NPA - 1) / NPA, 256, 0, stream>>>(
            qkv, vbf, out_e, cobf, rowptr, bucket, bsrc, dstof, agg, eagg);
        node_kernel_big<<<(N_NODES + NPB3B - 1) / NPB3B, 192, 0, stream>>>(
            x, agg, eagg, clw, clb, nlw, nlb, ln_h_g, ln_h_b, out_h);
        eln_kernel<true><<<(N_EDGES * 4) / 256, 256, 0, stream>>>(
            conn, cobf, ln_e_g, ln_e_b, out_e);
    } else if (B) {
        edge_kernel<false><<<N_EDGES / TILE_E, 256, 0, stream>>>(
            conn, eidx, qkv, e_w, e_b, nullptr, out_e);
        agg_kernel<true, false><<<(N_NODES + NPA - 1) / NPA, 256, 0, stream>>>(
            qkv, vbf, out_e, nullptr, rowptr, bucket, bsrc, dstof, agg, eagg);
        node_kernel_big<<<(N_NODES + NPB3B - 1) / NPB3B, 192, 0, stream>>>(
            x, agg, eagg, clw, clb, nlw, nlb, ln_h_g, ln_h_b, out_h);
        eln_kernel<false><<<(N_EDGES * 4) / 256, 256, 0, stream>>>(
            conn, nullptr, ln_e_g, ln_e_b, out_e);
    } else {
        edge_kernel<false><<<N_EDGES / TILE_E, 256, 0, stream>>>(
            conn, eidx, qkv, e_w, e_b, nullptr, out_e);
        node_kernel<<<(N_NODES + NPB3 - 1) / NPB3, 192, 0, stream>>>(
            x, qkv, out_e, rowptr, bucket, bsrc,
            clw, clb, nlw, nlb, ln_h_g, ln_h_b, out_h);
        eln_kernel<false><<<(N_EDGES * 4) / 256, 256, 0, stream>>>(
            conn, nullptr, ln_e_g, ln_e_b, out_e);
    }
}

// Round 15
// 1224.812 us; speedup vs baseline: 1.0604x; 1.0428x over previous
//
#include <hip/hip_runtime.h>
#include <math.h>

#define N_NODES 50000
#define N_EDGES 800000
#define H 96
#define QKV_N 288

#define NPB1 32   // nodes per block, qkv kernel
#define NPB3 4    // nodes per block, node kernel (gather fallback, R7-proven)
#define NPB3B 8   // nodes per block, node kernel (big path, streaming)
#define NPA 32    // nodes per agg block

typedef __attribute__((ext_vector_type(8))) short short8;   // 8 bf16 = 4 VGPRs
typedef __attribute__((ext_vector_type(4))) float f32x4;    // MFMA accumulator

// float -> bf16 (RNE) — used for storage roundings (vbf, cobf).
__device__ __forceinline__ short f2bf(float f) {
    union { float f; unsigned u; } v; v.f = f;
    unsigned r = v.u + 0x7FFFu + ((v.u >> 16) & 1u);
    return (short)(r >> 16);
}
__device__ __forceinline__ float bf2f(unsigned short h) {
    union { unsigned u; float f; } v; v.u = ((unsigned)h) << 16;
    return v.f;
}

// TRUNCATION hi/lo split (R12-proven): hi = top 16 bits (exact); residual is
// exactly representable; lo = trunc-bf16(residual). Dropped err <= 2^-16|f|.
__device__ __forceinline__ void ld_frag_split(const float* __restrict__ p,
                                              short8& hi, short8& lo) {
    float4 a = *(const float4*)p;
    float4 b = *(const float4*)(p + 4);
    float f[8] = {a.x, a.y, a.z, a.w, b.x, b.y, b.z, b.w};
    #pragma unroll
    for (int j = 0; j < 8; ++j) {
        union { float f; unsigned u; } v; v.f = f[j];
        hi[j] = (short)(v.u >> 16);
        union { unsigned u; float f; } h; h.u = v.u & 0xFFFF0000u;
        union { float f; unsigned u; } l; l.f = f[j] - h.f;
        lo[j] = (short)(l.u >> 16);
    }
}

// ---------------------------------------------------------------------------
// Kernel 1: qkv[n, t] = dot(x[n, :], qkv_w[t, :]) + qkv_b[t]   (t < 288)
// Also emits V as bf16 (vbf) for the L2-resident agg gather.
// ---------------------------------------------------------------------------
__global__ __launch_bounds__(QKV_N) void qkv_kernel(
    const float* __restrict__ x, const float* __restrict__ qw,
    const float* __restrict__ qb, float* __restrict__ qkv,
    unsigned short* __restrict__ vbf)
{
    __shared__ __align__(16) float xs[H];
    const int t = threadIdx.x;

    float w[H];
    #pragma unroll
    for (int k4 = 0; k4 < H; k4 += 4) {
        float4 v = *(const float4*)(qw + (size_t)t * H + k4);
        w[k4] = v.x; w[k4 + 1] = v.y; w[k4 + 2] = v.z; w[k4 + 3] = v.w;
    }
    const float bias = qb[t];

    const int n0 = blockIdx.x * NPB1;
    for (int nn = 0; nn < NPB1; ++nn) {
        const int node = n0 + nn;
        if (node >= N_NODES) break;          // block-uniform
        __syncthreads();
        if (t < H) xs[t] = x[(size_t)node * H + t];
        __syncthreads();
        float acc = bias;
        #pragma unroll
        for (int k4 = 0; k4 < H; k4 += 4) {
            float4 c = *(const float4*)(xs + k4);
            acc += c.x * w[k4] + c.y * w[k4 + 1] + c.z * w[k4 + 2] + c.w * w[k4 + 3];
        }
        qkv[(size_t)node * QKV_N + t] = acc;
        if (vbf && t >= 2 * H)
            vbf[(size_t)node * H + (t - 2 * H)] = (unsigned short)f2bf(acc);
    }
}

// ---------------------------------------------------------------------------
// CSR build: histogram -> scan -> scatter   (proven R4-R12)
// ---------------------------------------------------------------------------
__global__ __launch_bounds__(256) void hist_kernel(const int* __restrict__ eidx,
                                                   int* __restrict__ hist) {
    const int e = blockIdx.x * 256 + threadIdx.x;
    if (e < N_EDGES) atomicAdd(&hist[eidx[e]], 1);
}

#define SCAN_CH 49   // 1024*49 = 50176 >= 50000
__global__ __launch_bounds__(1024) void scan_kernel(int* __restrict__ hist,
                                                    int* __restrict__ rowptr) {
    __shared__ int sums[1024];
    const int t = threadIdx.x;
    const int st = t * SCAN_CH;
    int loc = 0;
    for (int k = 0; k < SCAN_CH; ++k) {
        const int i = st + k;
        if (i < N_NODES) loc += hist[i];
    }
    sums[t] = loc;
    __syncthreads();
    for (int off = 1; off < 1024; off <<= 1) {
        int add = (t >= off) ? sums[t - off] : 0;
        __syncthreads();
        sums[t] += add;
        __syncthreads();
    }
    int run = sums[t] - loc;     // exclusive prefix of this thread's chunk
    for (int k = 0; k < SCAN_CH; ++k) {
        const int i = st + k;
        if (i < N_NODES) {
            const int v = hist[i];
            rowptr[i] = run;
            hist[i]   = run;     // hist becomes the scatter cursor
            run += v;
        }
    }
    if (t == 1023) rowptr[N_NODES] = run;   // = N_EDGES
}

__global__ __launch_bounds__(256) void scatter_kernel(const int* __restrict__ eidx,
                                                      int* __restrict__ cursor,
                                                      int* __restrict__ bucket,
                                                      int* __restrict__ bsrc,
                                                      int* __restrict__ dstof) {
    const int e = blockIdx.x * 256 + threadIdx.x;
    if (e < N_EDGES) {
        const int dst = eidx[e];
        const int src = eidx[N_EDGES + e];
        const int pos = atomicAdd(&cursor[dst], 1);
        bucket[pos] = e;
        bsrc[pos]   = src;
        if (dstof) dstof[pos] = dst;
    }
}

// ---------------------------------------------------------------------------
// Kernel 2 (MFMA, bf16x3 trunc-split, fp32 eh tile — R12-verbatim).
// COBF: co -> bf16 co_bf (Tier A). !COBF: co fp32 -> out_e (Tier B/C).
// Abandoned after measured refutation: LN fusion (R4/R10/R11), bf16 eh tile
// (R13), early Q/K prefetch (R14), bf16 Q/K (precision: tail c1 err ~0.05 ->
// sqrt-amplified ~0.22 > 0.12 threshold, same mechanism as R2's failure).
// ---------------------------------------------------------------------------
#define TILE_E 64
#define EH_LD 196

template <bool COBF>
__global__ __launch_bounds__(256) void edge_kernel(
    const float* __restrict__ conn, const int* __restrict__ eidx,
    const float* __restrict__ qkv,
    const float* __restrict__ ew, const float* __restrict__ eb,
    unsigned short* __restrict__ co_bf, float* __restrict__ out_e)
{
    __shared__ __align__(16) float eh[TILE_E * EH_LD];   // 64 x 196 f32 = 50176 B

    const int t    = threadIdx.x;
    const int wave = t >> 6;
    const int lane = t & 63;
    const int lr   = lane & 15;
    const int lg16 = lane >> 4;

    // ---- B fragments (hi+lo): e_w rows are B^T rows ----
    short8 bwh[3][3], bwl[3][3];
    #pragma unroll
    for (int f = 0; f < 3; ++f) {
        const int tcol = 16 * (3 * wave + f) + lr;
        #pragma unroll
        for (int kc = 0; kc < 3; ++kc)
            ld_frag_split(ew + (size_t)tcol * H + 32 * kc + 8 * lg16,
                          bwh[f][kc], bwl[f][kc]);
    }

    const int e0 = blockIdx.x * TILE_E;

    f32x4 acc[4][3];
    #pragma unroll
    for (int mt = 0; mt < 4; ++mt)
        #pragma unroll
        for (int f = 0; f < 3; ++f)
            acc[mt][f] = (f32x4){0.f, 0.f, 0.f, 0.f};

    #pragma unroll
    for (int mt = 0; mt < 4; ++mt) {
        const int erow = e0 + 16 * mt + lr;
        short8 ah[3], al[3];
        #pragma unroll
        for (int kc = 0; kc < 3; ++kc)
            ld_frag_split(conn + (size_t)erow * H + 32 * kc + 8 * lg16,
                          ah[kc], al[kc]);
        #pragma unroll
        for (int f = 0; f < 3; ++f) {
            #pragma unroll
            for (int kc = 0; kc < 3; ++kc) {
                acc[mt][f] = __builtin_amdgcn_mfma_f32_16x16x32_bf16(
                                 ah[kc], bwl[f][kc], acc[mt][f], 0, 0, 0);
                acc[mt][f] = __builtin_amdgcn_mfma_f32_16x16x32_bf16(
                                 al[kc], bwh[f][kc], acc[mt][f], 0, 0, 0);
                acc[mt][f] = __builtin_amdgcn_mfma_f32_16x16x32_bf16(
                                 ah[kc], bwh[f][kc], acc[mt][f], 0, 0, 0);
            }
        }
    }

    // ---- write Eh (+bias) to LDS (fp32) ----
    #pragma unroll
    for (int mt = 0; mt < 4; ++mt) {
        #pragma unroll
        for (int f = 0; f < 3; ++f) {
            const int col = 16 * (3 * wave + f) + lr;
            const float bias = eb[col];
            #pragma unroll
            for (int r = 0; r < 4; ++r) {
                const int row = 16 * mt + 4 * lg16 + r;
                eh[row * EH_LD + col] = acc[mt][f][r] + bias;
            }
        }
    }
    __syncthreads();

    // ---- pointwise: lane q4 owns cols [24*q4, 24*q4+24) ----
    const int e_loc = t >> 2;
    const int q4    = t & 3;
    const int e     = e0 + e_loc;
    const int dst   = eidx[e];
    const int src   = eidx[N_EDGES + e];
    const float4* qQ4 = (const float4*)(qkv + (size_t)dst * QKV_N) + 6 * q4;
    const float4* qK4 = (const float4*)(qkv + (size_t)src * QKV_N + H) + 6 * q4;
    float4*          oe4 = (float4*)(out_e + (size_t)e * H) + 6 * q4;
    unsigned short*  cb  = COBF ? (co_bf + (size_t)e * H + 24 * q4) : nullptr;
    const float*  ehr = &eh[e_loc * EH_LD + 24 * q4];

    #pragma unroll
    for (int i = 0; i < 6; ++i) {
        const float4 q  = qQ4[i];
        const float4 k  = qK4[i];
        const float4 w4 = *(const float4*)(ehr + 4 * i);
        const float4 b4 = *(const float4*)(ehr + 4 * i + H);
        float4 co4;
        #pragma unroll
        for (int jj = 0; jj < 4; ++jj) {
            const float c1 = (q[jj] + k[jj]) * w4[jj];
            const float c2 = copysignf(sqrtf(fabsf(c1)), c1);
            co4[jj] = fmaxf(c2 + b4[jj], 0.f);
        }
        if (COBF) {
            ushort4 pk;
            pk.x = (unsigned short)f2bf(co4[0]);
            pk.y = (unsigned short)f2bf(co4[1]);
            pk.z = (unsigned short)f2bf(co4[2]);
            pk.w = (unsigned short)f2bf(co4[3]);
            *(ushort4*)(cb + 4 * i) = pk;
        } else {
            oe4[i] = co4;
        }
    }
}

// ---------------------------------------------------------------------------
// eln: out_e = LN(conn + co). COBF: co from bf16 co_bf; else in-place fp32.
// ---------------------------------------------------------------------------
template <bool COBF>
__global__ __launch_bounds__(256) void eln_kernel(
    const float* __restrict__ conn, const unsigned short* __restrict__ co_bf,
    const float* __restrict__ ln_g, const float* __restrict__ ln_b,
    float* __restrict__ out_e)
{
    const int tt   = blockIdx.x * 256 + threadIdx.x;
    const size_t e = (size_t)(tt >> 2);
    const int q4   = tt & 3;
    const float4* cn4 = (const float4*)(conn + e * H) + 6 * q4;
    float4*       oe4 = (float4*)(out_e + e * H) + 6 * q4;
    const float4* g4  = (const float4*)ln_g + 6 * q4;
    const float4* b4  = (const float4*)ln_b + 6 * q4;

    float4 v[6];
    float s = 0.f, s2 = 0.f;
    if (COBF) {
        const short8* cb8 = (const short8*)(co_bf + e * H + 24 * q4);
        #pragma unroll
        for (int j = 0; j < 3; ++j) {
            const short8 c8 = cb8[j];
            const float4 cA = cn4[2 * j];
            const float4 cB = cn4[2 * j + 1];
            #pragma unroll
            for (int k = 0; k < 4; ++k) {
                const float a = cA[k] + bf2f((unsigned short)c8[k]);
                const float b = cB[k] + bf2f((unsigned short)c8[4 + k]);
                v[2 * j][k] = a; v[2 * j + 1][k] = b;
                s += a + b; s2 += a * a + b * b;
            }
        }
    } else {
        #pragma unroll
        for (int i = 0; i < 6; ++i) {
            const float4 c = cn4[i];
            const float4 o = oe4[i];
            float4 val;
            #pragma unroll
            for (int jj = 0; jj < 4; ++jj) {
                val[jj] = c[jj] + o[jj];
                s += val[jj]; s2 += val[jj] * val[jj];
            }
            v[i] = val;
        }
    }
    s  += __shfl_xor(s, 1);  s  += __shfl_xor(s, 2);
    s2 += __shfl_xor(s2, 1); s2 += __shfl_xor(s2, 2);
    const float mean = s * (1.f / H);
    const float var  = s2 * (1.f / H) - mean * mean;
    const float rs   = rsqrtf(var + 1e-5f);
    #pragma unroll
    for (int i = 0; i < 6; ++i) {
        const float4 g = g4[i], b = b4[i];
        float4 o;
        #pragma unroll
        for (int jj = 0; jj < 4; ++jj)
            o[jj] = (v[i][jj] - mean) * rs * g[jj] + b[jj];
        oe4[i] = o;
    }
}

// ---------------------------------------------------------------------------
// agg_kernel: node-aligned segmented sum (structure proven R8-R12).
// ---------------------------------------------------------------------------
template <bool VBF, bool COBF>
__global__ __launch_bounds__(256) void agg_kernel(
    const float* __restrict__ qkv, const unsigned short* __restrict__ vbf,
    const float* __restrict__ co, const unsigned short* __restrict__ co_bf,
    const int* __restrict__ rowptr, const int* __restrict__ bucket,
    const int* __restrict__ bsrc, const int* __restrict__ dstof,
    float* __restrict__ agg, float* __restrict__ eagg)
{
    __shared__ float accA[NPA][H];
    __shared__ float accE[NPA][H];
    const int t = threadIdx.x;

    for (int i = t; i < NPA * H; i += 256) {
        ((float*)accA)[i] = 0.f;
        ((float*)accE)[i] = 0.f;
    }
    __syncthreads();

    const int n0   = blockIdx.x * NPA;
    const int nend = (n0 + NPA < N_NODES) ? (n0 + NPA) : N_NODES;
    const int P0 = rowptr[n0], P1 = rowptr[nend];
    const int count = P1 - P0;
    const int quad = t >> 2, q4 = t & 3;
    const int len  = (count + 63) >> 6;
    int p    = P0 + quad * len;
    int pend = p + len; if (pend > P1) pend = P1;

    float4 va[6], ve[6];
    #pragma unroll
    for (int i = 0; i < 6; ++i) { va[i] = (float4){0,0,0,0}; ve[i] = (float4){0,0,0,0}; }
    int cur = -1;

    for (; p < pend; ++p) {
        const int slot = dstof[p] - n0;
        if (slot != cur) {
            if (cur >= 0) {
                #pragma unroll
                for (int i = 0; i < 6; ++i)
                    #pragma unroll
                    for (int jj = 0; jj < 4; ++jj) {
                        atomicAdd(&accA[cur][24 * q4 + 4 * i + jj], va[i][jj]);
                        atomicAdd(&accE[cur][24 * q4 + 4 * i + jj], ve[i][jj]);
                    }
                #pragma unroll
                for (int i = 0; i < 6; ++i) { va[i] = (float4){0,0,0,0}; ve[i] = (float4){0,0,0,0}; }
            }
            cur = slot;
        }
        const int e  = bucket[p];
        const int sv = bsrc[p];
        if (VBF) {
            const short8* vb8 = (const short8*)(vbf + (size_t)sv * H + 24 * q4);
            #pragma unroll
            for (int j = 0; j < 3; ++j) {
                const short8 v8 = vb8[j];
                #pragma unroll
                for (int k = 0; k < 8; ++k) {
                    const int idx = 8 * j + k;
                    va[idx >> 2][idx & 3] += bf2f((unsigned short)v8[k]);
                }
            }
        } else {
            const float4* v4 = (const float4*)(qkv + (size_t)sv * QKV_N + 2 * H) + 6 * q4;
            #pragma unroll
            for (int i = 0; i < 6; ++i) {
                const float4 a = v4[i];
                #pragma unroll
                for (int jj = 0; jj < 4; ++jj) va[i][jj] += a[jj];
            }
        }
        if (COBF) {
            const short8* cb8 = (const short8*)(co_bf + (size_t)e * H + 24 * q4);
            #pragma unroll
            for (int j = 0; j < 3; ++j) {
                const short8 c8 = cb8[j];
                #pragma unroll
                for (int k = 0; k < 8; ++k) {
                    const int idx = 8 * j + k;
                    ve[idx >> 2][idx & 3] += bf2f((unsigned short)c8[k]);
                }
            }
        } else {
            const float4* c4 = (const float4*)(co + (size_t)e * H) + 6 * q4;
            #pragma unroll
            for (int i = 0; i < 6; ++i) {
                const float4 b = c4[i];
                #pragma unroll
                for (int jj = 0; jj < 4; ++jj) ve[i][jj] += b[jj];
            }
        }
    }
    if (cur >= 0) {
        #pragma unroll
        for (int i = 0; i < 6; ++i)
            #pragma unroll
            for (int jj = 0; jj < 4; ++jj) {
                atomicAdd(&accA[cur][24 * q4 + 4 * i + jj], va[i][jj]);
                atomicAdd(&accE[cur][24 * q4 + 4 * i + jj], ve[i][jj]);
            }
    }
    __syncthreads();

    const int nloc = nend - n0;
    for (int i = t; i < nloc * H; i += 256) {
        const int r = i / H, c = i - r * H;
        agg [(size_t)(n0 + r) * H + c] = accA[r][c];
        eagg[(size_t)(n0 + r) * H + c] = accE[r][c];
    }
}

// ---------------------------------------------------------------------------
// Kernel 3a (big path): node GEMVs + LN, streaming agg/eagg
// ---------------------------------------------------------------------------
__global__ __launch_bounds__(192) void node_kernel_big(
    const float* __restrict__ x,
    const float* __restrict__ agg, const float* __restrict__ eagg,
    const float* __restrict__ clw, const float* __restrict__ clb,
    const float* __restrict__ nlw, const float* __restrict__ nlb,
    const float* __restrict__ ln_g, const float* __restrict__ ln_b,
    float* __restrict__ out_h)
{
    __shared__ __align__(16) float ga[H];
    __shared__ __align__(16) float sa[H];
    __shared__ float red0[H], red1[H];
    const int t = threadIdx.x;

    float w[H];
    {
        const float* wsrc = (t < H) ? (clw + (size_t)t * H) : (nlw + (size_t)(t - H) * H);
        #pragma unroll
        for (int k4 = 0; k4 < H; k4 += 4) {
            float4 v = *(const float4*)(wsrc + k4);
            w[k4] = v.x; w[k4 + 1] = v.y; w[k4 + 2] = v.z; w[k4 + 3] = v.w;
        }
    }
    const float bias = (t < H) ? clb[t] : nlb[t - H];
    const float lg = (t >= H) ? ln_g[t - H] : 0.f;
    const float lb = (t >= H) ? ln_b[t - H] : 0.f;

    const int n0 = blockIdx.x * NPB3B;
    for (int nn = 0; nn < NPB3B; ++nn) {
        const int node = n0 + nn;
        if (node >= N_NODES) break;            // block-uniform
        __syncthreads();
        if (t < H)       ga[t]     = eagg[(size_t)node * H + t];
        else             sa[t - H] = agg[(size_t)node * H + (t - H)];
        __syncthreads();

        if (t < H) {
            float acc = bias;
            #pragma unroll
            for (int k4 = 0; k4 < H; k4 += 4) {
                float4 c = *(const float4*)(ga + k4);
                acc += c.x * w[k4] + c.y * w[k4 + 1] + c.z * w[k4 + 2] + c.w * w[k4 + 3];
            }
            sa[t] += acc;
        }
        __syncthreads();

        float val = 0.f;
        if (t >= H) {
            const int tt = t - H;
            float acc = bias;
            #pragma unroll
            for (int k4 = 0; k4 < H; k4 += 4) {
                float4 c = *(const float4*)(sa + k4);
                acc += c.x * w[k4] + c.y * w[k4 + 1] + c.z * w[k4 + 2] + c.w * w[k4 + 3];
            }
            val = acc + x[(size_t)node * H + tt];
            red0[tt] = val;
            red1[tt] = val * val;
        }
        __syncthreads();
        if (t < 32) { red0[t] += red0[t + 64]; red1[t] += red1[t + 64]; }
        __syncthreads();
        for (int s = 32; s > 0; s >>= 1) {
            if (t < s) { red0[t] += red0[t + s]; red1[t] += red1[t + s]; }
            __syncthreads();
        }
        if (t >= H) {
            const float mean = red0[0] * (1.f / H);
            const float var  = red1[0] * (1.f / H) - mean * mean;
            const float r    = rsqrtf(var + 1e-5f);
            out_h[(size_t)node * H + (t - H)] = (val - mean) * r * lg + lb;
        }
    }
}

// ---------------------------------------------------------------------------
// Kernel 3b (fallback, R7-proven): node path via CSR gather
// ---------------------------------------------------------------------------
__global__ __launch_bounds__(192) void node_kernel(
    const float* __restrict__ x, const float* __restrict__ qkv,
    const float* __restrict__ co_f32,                 // = out_e (holds raw co)
    const int* __restrict__ rowptr, const int* __restrict__ bucket,
    const int* __restrict__ bsrc,
    const float* __restrict__ clw, const float* __restrict__ clb,
    const float* __restrict__ nlw, const float* __restrict__ nlb,
    const float* __restrict__ ln_g, const float* __restrict__ ln_b,
    float* __restrict__ out_h)
{
    __shared__ __align__(16) float ga[H];
    __shared__ __align__(16) float sa[H];
    __shared__ float pa2[192], pe2[192];
    __shared__ float red0[H], red1[H];
    const int t = threadIdx.x;
    const int col = (t < H) ? t : (t - H);
    const int par = (t < H) ? 0 : 1;

    float w[H];
    {
        const float* wsrc = (t < H) ? (clw + (size_t)t * H) : (nlw + (size_t)(t - H) * H);
        #pragma unroll
        for (int k4 = 0; k4 < H; k4 += 4) {
            float4 v = *(const float4*)(wsrc + k4);
            w[k4] = v.x; w[k4 + 1] = v.y; w[k4 + 2] = v.z; w[k4 + 3] = v.w;
        }
    }
    const float bias = (t < H) ? clb[t] : nlb[t - H];
    const float lg = (t >= H) ? ln_g[t - H] : 0.f;
    const float lb = (t >= H) ? ln_b[t - H] : 0.f;

    const int n0 = blockIdx.x * NPB3;
    for (int nn = 0; nn < NPB3; ++nn) {
        const int node = n0 + nn;
        if (node >= N_NODES) break;            // block-uniform
        const int r0 = rowptr[node], r1 = rowptr[node + 1];

        float pa = 0.f, pe = 0.f;
        for (int j = r0 + par; j < r1; j += 2) {
            const int ee = bucket[j];
            const int sv = bsrc[j];
            pa += qkv[(size_t)sv * QKV_N + 2 * H + col];
            pe += co_f32[(size_t)ee * H + col];
        }
        __syncthreads();
        pa2[t] = pa; pe2[t] = pe;
        __syncthreads();
        if (t < H) ga[t]      = pe2[t] + pe2[t + H];
        else       sa[t - H]  = pa2[t - H] + pa2[t];
        __syncthreads();

        if (t < H) {
            float acc = bias;
            #pragma unroll
            for (int k4 = 0; k4 < H; k4 += 4) {
                float4 c = *(const float4*)(ga + k4);
                acc += c.x * w[k4] + c.y * w[k4 + 1] + c.z * w[k4 + 2] + c.w * w[k4 + 3];
            }
            sa[t] += acc;
        }
        __syncthreads();

        float val = 0.f;
        if (t >= H) {
            const int tt = t - H;
            float acc = bias;
            #pragma unroll
            for (int k4 = 0; k4 < H; k4 += 4) {
                float4 c = *(const float4*)(sa + k4);
                acc += c.x * w[k4] + c.y * w[k4 + 1] + c.z * w[k4 + 2] + c.w * w[k4 + 3];
            }
            val = acc + x[(size_t)node * H + tt];
            red0[tt] = val;
            red1[tt] = val * val;
        }
        __syncthreads();
        if (t < 32) { red0[t] += red0[t + 64]; red1[t] += red1[t + 64]; }
        __syncthreads();
        for (int s = 32; s > 0; s >>= 1) {
            if (t < s) { red0[t] += red0[t + s]; red1[t] += red1[t + s]; }
            __syncthreads();
        }
        if (t >= H) {
            const float mean = red0[0] * (1.f / H);
            const float var  = red1[0] * (1.f / H) - mean * mean;
            const float r    = rsqrtf(var + 1e-5f);
            out_h[(size_t)node * H + (t - H)] = (val - mean) * r * lg + lb;
        }
    }
}

// ---------------------------------------------------------------------------
extern "C" void kernel_launch(void* const* d_in, const int* in_sizes, int n_in,
                              void* d_out, int out_size, void* d_ws, size_t ws_size,
                              hipStream_t stream) {
    const float* x      = (const float*)d_in[0];
    const float* conn   = (const float*)d_in[1];
    const int*   eidx   = (const int*)  d_in[2];
    const float* qkv_w  = (const float*)d_in[3];
    const float* qkv_b  = (const float*)d_in[4];
    const float* e_w    = (const float*)d_in[5];
    const float* e_b    = (const float*)d_in[6];
    const float* clw    = (const float*)d_in[7];
    const float* clb    = (const float*)d_in[8];
    const float* nlw    = (const float*)d_in[9];
    const float* nlb    = (const float*)d_in[10];
    const float* ln_h_g = (const float*)d_in[11];
    const float* ln_h_b = (const float*)d_in[12];
    const float* ln_e_g = (const float*)d_in[13];
    const float* ln_e_b = (const float*)d_in[14];

    float* out_h = (float*)d_out;                        // 50000*96
    float* out_e = out_h + (size_t)N_NODES * H;          // 800000*96

    // ---- ws: qkv | rowptr | hist | bucket | bsrc | dstof | agg | eagg | vbf | cobf
    char* base = (char*)d_ws;
    float* qkv = (float*)base;
    size_t off = (size_t)N_NODES * QKV_N * sizeof(float);        // 57.6 MB
    int* rowptr = (int*)(base + off); off += (size_t)(N_NODES + 1) * 4;
    int* hist   = (int*)(base + off); off += (size_t)N_NODES * 4;
    int* bucket = (int*)(base + off); off += (size_t)N_EDGES * 4;
    int* bsrc   = (int*)(base + off); off += (size_t)N_EDGES * 4;        // 64.4 MB
    int*   dstof = (int*)(base + off);  off += (size_t)N_EDGES * 4;      // 67.6
    float* agg   = (float*)(base + off); off += (size_t)N_NODES * H * 4;
    float* eagg  = (float*)(base + off); off += (size_t)N_NODES * H * 4; // 106 MB
    unsigned short* vbf = (unsigned short*)(base + off);
    off += (size_t)N_NODES * H * 2;                                      // 115.6 MB
    const size_t need_B = off;
    unsigned short* cobf = (unsigned short*)(base + off);
    off += (size_t)N_EDGES * H * 2;                                      // 269.2 MB
    const size_t need_A = off;

    const bool A = ws_size >= need_A;
    const bool B = !A && ws_size >= need_B;

    hipMemsetAsync(hist, 0, (size_t)N_NODES * 4, stream);

    qkv_kernel    <<<(N_NODES + NPB1 - 1) / NPB1, QKV_N, 0, stream>>>(
        x, qkv_w, qkv_b, qkv, (A || B) ? vbf : nullptr);
    hist_kernel   <<<(N_EDGES + 255) / 256, 256, 0, stream>>>(eidx, hist);
    scan_kernel   <<<1, 1024, 0, stream>>>(hist, rowptr);
    scatter_kernel<<<(N_EDGES + 255) / 256, 256, 0, stream>>>(eidx, hist, bucket, bsrc,
                                                              (A || B) ? dstof : nullptr);

    if (A) {
        edge_kernel<true><<<N_EDGES / TILE_E, 256, 0, stream>>>(
            conn, eidx, qkv, e_w, e_b, cobf, out_e);
        agg_kernel<true, true><<<(N_NODES + NPA - 1) / NPA, 256, 0, stream>>>(
            qkv, vbf, out_e, cobf, rowptr, bucket, bsrc, dstof, agg, eagg);
        node_kernel_big<<<(N_NODES + NPB3B - 1) / NPB3B, 192, 0, stream>>>(
            x, agg, eagg, clw, clb, nlw, nlb, ln_h_g, ln_h_b, out_h);
        eln_kernel<true><<<(N_EDGES * 4) / 256, 256, 0, stream>>>(
            conn, cobf, ln_e_g, ln_e_b, out_e);
    } else if (B) {
        edge_kernel<false><<<N_EDGES / TILE_E, 256, 0, stream>>>(
            conn, eidx, qkv, e_w, e_b, nullptr, out_e);
        agg_kernel<true, false><<<(N_NODES + NPA - 1) / NPA, 256, 0, stream>>>(
            qkv, vbf, out_e, nullptr, rowptr, bucket, bsrc, dstof, agg, eagg);
        node_kernel_big<<<(N_NODES + NPB3B - 1) / NPB3B, 192, 0, stream>>>(
            x, agg, eagg, clw, clb, nlw, nlb, ln_h_g, ln_h_b, out_h);
        eln_kernel<false><<<(N_EDGES * 4) / 256, 256, 0, stream>>>(
            conn, nullptr, ln_e_g, ln_e_b, out_e);
    } else {
        edge_kernel<false><<<N_EDGES / TILE_E, 256, 0, stream>>>(
            conn, eidx, qkv, e_w, e_b, nullptr, out_e);
        node_kernel<<<(N_NODES + NPB3 - 1) / NPB3, 192, 0, stream>>>(
            x, qkv, out_e, rowptr, bucket, bsrc,
            clw, clb, nlw, nlb, ln_h_g, ln_h_b, out_h);
        eln_kernel<false><<<(N_EDGES * 4) / 256, 256, 0, stream>>>(
            conn, nullptr, ln_e_g, ln_e_b, out_e);
    }
}

// Round 16
// 1193.949 us; speedup vs baseline: 1.0879x; 1.0258x over previous
//
#include <hip/hip_runtime.h>
#include <math.h>

#define N_NODES 50000
#define N_EDGES 800000
#define H 96
#define QKV_N 288

#define NPB1 32   // nodes per block, qkv kernel
#define NPB3 4    // nodes per block, node kernel (gather fallback, R7-proven)
#define NPB3B 8   // nodes per block, node kernel (big path, streaming)
#define NPA 32    // nodes per agg block

typedef __attribute__((ext_vector_type(8))) short short8;   // 8 bf16 = 4 VGPRs
typedef __attribute__((ext_vector_type(4))) float f32x4;    // MFMA accumulator

// float -> bf16 (RNE) — used for storage roundings (vbf, cobf).
__device__ __forceinline__ short f2bf(float f) {
    union { float f; unsigned u; } v; v.f = f;
    unsigned r = v.u + 0x7FFFu + ((v.u >> 16) & 1u);
    return (short)(r >> 16);
}
__device__ __forceinline__ float bf2f(unsigned short h) {
    union { unsigned u; float f; } v; v.u = ((unsigned)h) << 16;
    return v.f;
}

// TRUNCATION hi/lo split (R12-proven): hi = top 16 bits (exact); residual is
// exactly representable; lo = trunc-bf16(residual). Dropped err <= 2^-16|f|.
__device__ __forceinline__ void ld_frag_split(const float* __restrict__ p,
                                              short8& hi, short8& lo) {
    float4 a = *(const float4*)p;
    float4 b = *(const float4*)(p + 4);
    float f[8] = {a.x, a.y, a.z, a.w, b.x, b.y, b.z, b.w};
    #pragma unroll
    for (int j = 0; j < 8; ++j) {
        union { float f; unsigned u; } v; v.f = f[j];
        hi[j] = (short)(v.u >> 16);
        union { unsigned u; float f; } h; h.u = v.u & 0xFFFF0000u;
        union { float f; unsigned u; } l; l.f = f[j] - h.f;
        lo[j] = (short)(l.u >> 16);
    }
}

// ---------------------------------------------------------------------------
// Kernel 1: qkv[n, t] = dot(x[n, :], qkv_w[t, :]) + qkv_b[t]   (t < 288)
// Also emits V as bf16 (vbf) for the L2-resident agg gather.
// ---------------------------------------------------------------------------
__global__ __launch_bounds__(QKV_N) void qkv_kernel(
    const float* __restrict__ x, const float* __restrict__ qw,
    const float* __restrict__ qb, float* __restrict__ qkv,
    unsigned short* __restrict__ vbf)
{
    __shared__ __align__(16) float xs[H];
    const int t = threadIdx.x;

    float w[H];
    #pragma unroll
    for (int k4 = 0; k4 < H; k4 += 4) {
        float4 v = *(const float4*)(qw + (size_t)t * H + k4);
        w[k4] = v.x; w[k4 + 1] = v.y; w[k4 + 2] = v.z; w[k4 + 3] = v.w;
    }
    const float bias = qb[t];

    const int n0 = blockIdx.x * NPB1;
    for (int nn = 0; nn < NPB1; ++nn) {
        const int node = n0 + nn;
        if (node >= N_NODES) break;          // block-uniform
        __syncthreads();
        if (t < H) xs[t] = x[(size_t)node * H + t];
        __syncthreads();
        float acc = bias;
        #pragma unroll
        for (int k4 = 0; k4 < H; k4 += 4) {
            float4 c = *(const float4*)(xs + k4);
            acc += c.x * w[k4] + c.y * w[k4 + 1] + c.z * w[k4 + 2] + c.w * w[k4 + 3];
        }
        qkv[(size_t)node * QKV_N + t] = acc;
        if (vbf && t >= 2 * H)
            vbf[(size_t)node * H + (t - 2 * H)] = (unsigned short)f2bf(acc);
    }
}

// ---------------------------------------------------------------------------
// CSR build: histogram -> scan -> scatter   (proven R4-R15)
// ---------------------------------------------------------------------------
__global__ __launch_bounds__(256) void hist_kernel(const int* __restrict__ eidx,
                                                   int* __restrict__ hist) {
    const int e = blockIdx.x * 256 + threadIdx.x;
    if (e < N_EDGES) atomicAdd(&hist[eidx[e]], 1);
}

#define SCAN_CH 49   // 1024*49 = 50176 >= 50000
__global__ __launch_bounds__(1024) void scan_kernel(int* __restrict__ hist,
                                                    int* __restrict__ rowptr) {
    __shared__ int sums[1024];
    const int t = threadIdx.x;
    const int st = t * SCAN_CH;
    int loc = 0;
    for (int k = 0; k < SCAN_CH; ++k) {
        const int i = st + k;
        if (i < N_NODES) loc += hist[i];
    }
    sums[t] = loc;
    __syncthreads();
    for (int off = 1; off < 1024; off <<= 1) {
        int add = (t >= off) ? sums[t - off] : 0;
        __syncthreads();
        sums[t] += add;
        __syncthreads();
    }
    int run = sums[t] - loc;     // exclusive prefix of this thread's chunk
    for (int k = 0; k < SCAN_CH; ++k) {
        const int i = st + k;
        if (i < N_NODES) {
            const int v = hist[i];
            rowptr[i] = run;
            hist[i]   = run;     // hist becomes the scatter cursor
            run += v;
        }
    }
    if (t == 1023) rowptr[N_NODES] = run;   // = N_EDGES
}

__global__ __launch_bounds__(256) void scatter_kernel(const int* __restrict__ eidx,
                                                      int* __restrict__ cursor,
                                                      int* __restrict__ bucket,
                                                      int* __restrict__ bsrc,
                                                      int* __restrict__ dstof) {
    const int e = blockIdx.x * 256 + threadIdx.x;
    if (e < N_EDGES) {
        const int dst = eidx[e];
        const int src = eidx[N_EDGES + e];
        const int pos = atomicAdd(&cursor[dst], 1);
        bucket[pos] = e;
        bsrc[pos]   = src;
        if (dstof) dstof[pos] = dst;
    }
}

// ---------------------------------------------------------------------------
// Kernel 2 (MFMA, bf16x3 trunc-split, fp32 eh tile — R12-verbatim).
// COBF: co -> bf16 co_bf (Tier A). !COBF: co fp32 -> out_e (Tier B/C).
// Abandoned after measured refutation: LN fusion HERE (R4/R10/R11), bf16 eh
// tile (R13), early Q/K prefetch (R14), bf16 Q/K (precision analysis).
// ---------------------------------------------------------------------------
#define TILE_E 64
#define EH_LD 196

template <bool COBF>
__global__ __launch_bounds__(256) void edge_kernel(
    const float* __restrict__ conn, const int* __restrict__ eidx,
    const float* __restrict__ qkv,
    const float* __restrict__ ew, const float* __restrict__ eb,
    unsigned short* __restrict__ co_bf, float* __restrict__ out_e)
{
    __shared__ __align__(16) float eh[TILE_E * EH_LD];   // 64 x 196 f32 = 50176 B

    const int t    = threadIdx.x;
    const int wave = t >> 6;
    const int lane = t & 63;
    const int lr   = lane & 15;
    const int lg16 = lane >> 4;

    // ---- B fragments (hi+lo): e_w rows are B^T rows ----
    short8 bwh[3][3], bwl[3][3];
    #pragma unroll
    for (int f = 0; f < 3; ++f) {
        const int tcol = 16 * (3 * wave + f) + lr;
        #pragma unroll
        for (int kc = 0; kc < 3; ++kc)
            ld_frag_split(ew + (size_t)tcol * H + 32 * kc + 8 * lg16,
                          bwh[f][kc], bwl[f][kc]);
    }

    const int e0 = blockIdx.x * TILE_E;

    f32x4 acc[4][3];
    #pragma unroll
    for (int mt = 0; mt < 4; ++mt)
        #pragma unroll
        for (int f = 0; f < 3; ++f)
            acc[mt][f] = (f32x4){0.f, 0.f, 0.f, 0.f};

    #pragma unroll
    for (int mt = 0; mt < 4; ++mt) {
        const int erow = e0 + 16 * mt + lr;
        short8 ah[3], al[3];
        #pragma unroll
        for (int kc = 0; kc < 3; ++kc)
            ld_frag_split(conn + (size_t)erow * H + 32 * kc + 8 * lg16,
                          ah[kc], al[kc]);
        #pragma unroll
        for (int f = 0; f < 3; ++f) {
            #pragma unroll
            for (int kc = 0; kc < 3; ++kc) {
                acc[mt][f] = __builtin_amdgcn_mfma_f32_16x16x32_bf16(
                                 ah[kc], bwl[f][kc], acc[mt][f], 0, 0, 0);
                acc[mt][f] = __builtin_amdgcn_mfma_f32_16x16x32_bf16(
                                 al[kc], bwh[f][kc], acc[mt][f], 0, 0, 0);
                acc[mt][f] = __builtin_amdgcn_mfma_f32_16x16x32_bf16(
                                 ah[kc], bwh[f][kc], acc[mt][f], 0, 0, 0);
            }
        }
    }

    // ---- write Eh (+bias) to LDS (fp32) ----
    #pragma unroll
    for (int mt = 0; mt < 4; ++mt) {
        #pragma unroll
        for (int f = 0; f < 3; ++f) {
            const int col = 16 * (3 * wave + f) + lr;
            const float bias = eb[col];
            #pragma unroll
            for (int r = 0; r < 4; ++r) {
                const int row = 16 * mt + 4 * lg16 + r;
                eh[row * EH_LD + col] = acc[mt][f][r] + bias;
            }
        }
    }
    __syncthreads();

    // ---- pointwise: lane q4 owns cols [24*q4, 24*q4+24) ----
    const int e_loc = t >> 2;
    const int q4    = t & 3;
    const int e     = e0 + e_loc;
    const int dst   = eidx[e];
    const int src   = eidx[N_EDGES + e];
    const float4* qQ4 = (const float4*)(qkv + (size_t)dst * QKV_N) + 6 * q4;
    const float4* qK4 = (const float4*)(qkv + (size_t)src * QKV_N + H) + 6 * q4;
    float4*          oe4 = (float4*)(out_e + (size_t)e * H) + 6 * q4;
    unsigned short*  cb  = COBF ? (co_bf + (size_t)e * H + 24 * q4) : nullptr;
    const float*  ehr = &eh[e_loc * EH_LD + 24 * q4];

    #pragma unroll
    for (int i = 0; i < 6; ++i) {
        const float4 q  = qQ4[i];
        const float4 k  = qK4[i];
        const float4 w4 = *(const float4*)(ehr + 4 * i);
        const float4 b4 = *(const float4*)(ehr + 4 * i + H);
        float4 co4;
        #pragma unroll
        for (int jj = 0; jj < 4; ++jj) {
            const float c1 = (q[jj] + k[jj]) * w4[jj];
            const float c2 = copysignf(sqrtf(fabsf(c1)), c1);
            co4[jj] = fmaxf(c2 + b4[jj], 0.f);
        }
        if (COBF) {
            ushort4 pk;
            pk.x = (unsigned short)f2bf(co4[0]);
            pk.y = (unsigned short)f2bf(co4[1]);
            pk.z = (unsigned short)f2bf(co4[2]);
            pk.w = (unsigned short)f2bf(co4[3]);
            *(ushort4*)(cb + 4 * i) = pk;
        } else {
            oe4[i] = co4;
        }
    }
}

// ---------------------------------------------------------------------------
// eln (Tier B/C only): out_e = LN(conn + co) in place (fp32 co in out_e).
// ---------------------------------------------------------------------------
__global__ __launch_bounds__(256) void eln_kernel(
    const float* __restrict__ conn,
    const float* __restrict__ ln_g, const float* __restrict__ ln_b,
    float* __restrict__ out_e)
{
    const int tt   = blockIdx.x * 256 + threadIdx.x;
    const size_t e = (size_t)(tt >> 2);
    const int q4   = tt & 3;
    const float4* cn4 = (const float4*)(conn + e * H) + 6 * q4;
    float4*       oe4 = (float4*)(out_e + e * H) + 6 * q4;
    const float4* g4  = (const float4*)ln_g + 6 * q4;
    const float4* b4  = (const float4*)ln_b + 6 * q4;

    float4 v[6];
    float s = 0.f, s2 = 0.f;
    #pragma unroll
    for (int i = 0; i < 6; ++i) {
        const float4 c = cn4[i];
        const float4 o = oe4[i];
        float4 val;
        #pragma unroll
        for (int jj = 0; jj < 4; ++jj) {
            val[jj] = c[jj] + o[jj];
            s += val[jj]; s2 += val[jj] * val[jj];
        }
        v[i] = val;
    }
    s  += __shfl_xor(s, 1);  s  += __shfl_xor(s, 2);
    s2 += __shfl_xor(s2, 1); s2 += __shfl_xor(s2, 2);
    const float mean = s * (1.f / H);
    const float var  = s2 * (1.f / H) - mean * mean;
    const float rs   = rsqrtf(var + 1e-5f);
    #pragma unroll
    for (int i = 0; i < 6; ++i) {
        const float4 g = g4[i], b = b4[i];
        float4 o;
        #pragma unroll
        for (int jj = 0; jj < 4; ++jj)
            o[jj] = (v[i][jj] - mean) * rs * g[jj] + b[jj];
        oe4[i] = o;
    }
}

// ---------------------------------------------------------------------------
// agg_kernel: node-aligned segmented sum (structure proven R8-R15).
// R16's single change: when COBF (Tier A), the edge-LN is FUSED here —
// each quad already owns a full cobf row per edge (same decomposition as the
// proven eln kernel, and agg has NO MFMA so the R4/R10/R11 failure context
// does not apply). Writes out_e = LN(conn + co); eln pass eliminated.
// ---------------------------------------------------------------------------
template <bool VBF, bool COBF>
__global__ __launch_bounds__(256) void agg_kernel(
    const float* __restrict__ qkv, const unsigned short* __restrict__ vbf,
    const float* __restrict__ co, const unsigned short* __restrict__ co_bf,
    const float* __restrict__ conn,
    const float* __restrict__ ln_g, const float* __restrict__ ln_b,
    float* __restrict__ out_e,
    const int* __restrict__ rowptr, const int* __restrict__ bucket,
    const int* __restrict__ bsrc, const int* __restrict__ dstof,
    float* __restrict__ agg, float* __restrict__ eagg)
{
    __shared__ float accA[NPA][H];
    __shared__ float accE[NPA][H];
    const int t = threadIdx.x;

    for (int i = t; i < NPA * H; i += 256) {
        ((float*)accA)[i] = 0.f;
        ((float*)accE)[i] = 0.f;
    }
    __syncthreads();

    const int n0   = blockIdx.x * NPA;
    const int nend = (n0 + NPA < N_NODES) ? (n0 + NPA) : N_NODES;
    const int P0 = rowptr[n0], P1 = rowptr[nend];
    const int count = P1 - P0;
    const int quad = t >> 2, q4 = t & 3;
    const int len  = (count + 63) >> 6;
    int p    = P0 + quad * len;
    int pend = p + len; if (pend > P1) pend = P1;

    float4 va[6], ve[6];
    #pragma unroll
    for (int i = 0; i < 6; ++i) { va[i] = (float4){0,0,0,0}; ve[i] = (float4){0,0,0,0}; }
    int cur = -1;

    for (; p < pend; ++p) {
        const int slot = dstof[p] - n0;
        if (slot != cur) {
            if (cur >= 0) {
                #pragma unroll
                for (int i = 0; i < 6; ++i)
                    #pragma unroll
                    for (int jj = 0; jj < 4; ++jj) {
                        atomicAdd(&accA[cur][24 * q4 + 4 * i + jj], va[i][jj]);
                        atomicAdd(&accE[cur][24 * q4 + 4 * i + jj], ve[i][jj]);
                    }
                #pragma unroll
                for (int i = 0; i < 6; ++i) { va[i] = (float4){0,0,0,0}; ve[i] = (float4){0,0,0,0}; }
            }
            cur = slot;
        }
        const int e  = bucket[p];
        const int sv = bsrc[p];
        if (VBF) {
            const short8* vb8 = (const short8*)(vbf + (size_t)sv * H + 24 * q4);
            #pragma unroll
            for (int j = 0; j < 3; ++j) {
                const short8 v8 = vb8[j];
                #pragma unroll
                for (int k = 0; k < 8; ++k) {
                    const int idx = 8 * j + k;
                    va[idx >> 2][idx & 3] += bf2f((unsigned short)v8[k]);
                }
            }
        } else {
            const float4* v4 = (const float4*)(qkv + (size_t)sv * QKV_N + 2 * H) + 6 * q4;
            #pragma unroll
            for (int i = 0; i < 6; ++i) {
                const float4 a = v4[i];
                #pragma unroll
                for (int jj = 0; jj < 4; ++jj) va[i][jj] += a[jj];
            }
        }
        if (COBF) {
            const short8* cb8 = (const short8*)(co_bf + (size_t)e * H + 24 * q4);
            short8 c8[3];
            c8[0] = cb8[0]; c8[1] = cb8[1]; c8[2] = cb8[2];
            const float4* cn4 = (const float4*)(conn + (size_t)e * H) + 6 * q4;
            float4 v_s[6];
            float s = 0.f, s2 = 0.f;
            #pragma unroll
            for (int j = 0; j < 3; ++j) {
                #pragma unroll
                for (int k = 0; k < 8; ++k) {
                    const int idx = 8 * j + k;
                    const float cov = bf2f((unsigned short)c8[j][k]);
                    ve[idx >> 2][idx & 3] += cov;
                    const float val = cn4[idx >> 2][idx & 3] + cov;
                    v_s[idx >> 2][idx & 3] = val;
                    s += val; s2 += val * val;
                }
            }
            // quad LN reduce (proven eln pattern; quad = 4 consecutive lanes)
            s  += __shfl_xor(s, 1);  s  += __shfl_xor(s, 2);
            s2 += __shfl_xor(s2, 1); s2 += __shfl_xor(s2, 2);
            const float mean = s * (1.f / H);
            const float var  = s2 * (1.f / H) - mean * mean;
            const float rs   = rsqrtf(var + 1e-5f);
            float4* oe4 = (float4*)(out_e + (size_t)e * H) + 6 * q4;
            const float4* g4 = (const float4*)ln_g + 6 * q4;
            const float4* b4 = (const float4*)ln_b + 6 * q4;
            #pragma unroll
            for (int i = 0; i < 6; ++i) {
                const float4 g = g4[i], b = b4[i];
                float4 o;
                #pragma unroll
                for (int jj = 0; jj < 4; ++jj)
                    o[jj] = (v_s[i][jj] - mean) * rs * g[jj] + b[jj];
                oe4[i] = o;
            }
        } else {
            const float4* c4 = (const float4*)(co + (size_t)e * H) + 6 * q4;
            #pragma unroll
            for (int i = 0; i < 6; ++i) {
                const float4 b = c4[i];
                #pragma unroll
                for (int jj = 0; jj < 4; ++jj) ve[i][jj] += b[jj];
            }
        }
    }
    if (cur >= 0) {
        #pragma unroll
        for (int i = 0; i < 6; ++i)
            #pragma unroll
            for (int jj = 0; jj < 4; ++jj) {
                atomicAdd(&accA[cur][24 * q4 + 4 * i + jj], va[i][jj]);
                atomicAdd(&accE[cur][24 * q4 + 4 * i + jj], ve[i][jj]);
            }
    }
    __syncthreads();

    const int nloc = nend - n0;
    for (int i = t; i < nloc * H; i += 256) {
        const int r = i / H, c = i - r * H;
        agg [(size_t)(n0 + r) * H + c] = accA[r][c];
        eagg[(size_t)(n0 + r) * H + c] = accE[r][c];
    }
}

// ---------------------------------------------------------------------------
// Kernel 3a (big path): node GEMVs + LN, streaming agg/eagg
// ---------------------------------------------------------------------------
__global__ __launch_bounds__(192) void node_kernel_big(
    const float* __restrict__ x,
    const float* __restrict__ agg, const float* __restrict__ eagg,
    const float* __restrict__ clw, const float* __restrict__ clb,
    const float* __restrict__ nlw, const float* __restrict__ nlb,
    const float* __restrict__ ln_g, const float* __restrict__ ln_b,
    float* __restrict__ out_h)
{
    __shared__ __align__(16) float ga[H];
    __shared__ __align__(16) float sa[H];
    __shared__ float red0[H], red1[H];
    const int t = threadIdx.x;

    float w[H];
    {
        const float* wsrc = (t < H) ? (clw + (size_t)t * H) : (nlw + (size_t)(t - H) * H);
        #pragma unroll
        for (int k4 = 0; k4 < H; k4 += 4) {
            float4 v = *(const float4*)(wsrc + k4);
            w[k4] = v.x; w[k4 + 1] = v.y; w[k4 + 2] = v.z; w[k4 + 3] = v.w;
        }
    }
    const float bias = (t < H) ? clb[t] : nlb[t - H];
    const float lg = (t >= H) ? ln_g[t - H] : 0.f;
    const float lb = (t >= H) ? ln_b[t - H] : 0.f;

    const int n0 = blockIdx.x * NPB3B;
    for (int nn = 0; nn < NPB3B; ++nn) {
        const int node = n0 + nn;
        if (node >= N_NODES) break;            // block-uniform
        __syncthreads();
        if (t < H)       ga[t]     = eagg[(size_t)node * H + t];
        else             sa[t - H] = agg[(size_t)node * H + (t - H)];
        __syncthreads();

        if (t < H) {
            float acc = bias;
            #pragma unroll
            for (int k4 = 0; k4 < H; k4 += 4) {
                float4 c = *(const float4*)(ga + k4);
                acc += c.x * w[k4] + c.y * w[k4 + 1] + c.z * w[k4 + 2] + c.w * w[k4 + 3];
            }
            sa[t] += acc;
        }
        __syncthreads();

        float val = 0.f;
        if (t >= H) {
            const int tt = t - H;
            float acc = bias;
            #pragma unroll
            for (int k4 = 0; k4 < H; k4 += 4) {
                float4 c = *(const float4*)(sa + k4);
                acc += c.x * w[k4] + c.y * w[k4 + 1] + c.z * w[k4 + 2] + c.w * w[k4 + 3];
            }
            val = acc + x[(size_t)node * H + tt];
            red0[tt] = val;
            red1[tt] = val * val;
        }
        __syncthreads();
        if (t < 32) { red0[t] += red0[t + 64]; red1[t] += red1[t + 64]; }
        __syncthreads();
        for (int s = 32; s > 0; s >>= 1) {
            if (t < s) { red0[t] += red0[t + s]; red1[t] += red1[t + s]; }
            __syncthreads();
        }
        if (t >= H) {
            const float mean = red0[0] * (1.f / H);
            const float var  = red1[0] * (1.f / H) - mean * mean;
            const float r    = rsqrtf(var + 1e-5f);
            out_h[(size_t)node * H + (t - H)] = (val - mean) * r * lg + lb;
        }
    }
}

// ---------------------------------------------------------------------------
// Kernel 3b (fallback, R7-proven): node path via CSR gather
// ---------------------------------------------------------------------------
__global__ __launch_bounds__(192) void node_kernel(
    const float* __restrict__ x, const float* __restrict__ qkv,
    const float* __restrict__ co_f32,                 // = out_e (holds raw co)
    const int* __restrict__ rowptr, const int* __restrict__ bucket,
    const int* __restrict__ bsrc,
    const float* __restrict__ clw, const float* __restrict__ clb,
    const float* __restrict__ nlw, const float* __restrict__ nlb,
    const float* __restrict__ ln_g, const float* __restrict__ ln_b,
    float* __restrict__ out_h)
{
    __shared__ __align__(16) float ga[H];
    __shared__ __align__(16) float sa[H];
    __shared__ float pa2[192], pe2[192];
    __shared__ float red0[H], red1[H];
    const int t = threadIdx.x;
    const int col = (t < H) ? t : (t - H);
    const int par = (t < H) ? 0 : 1;

    float w[H];
    {
        const float* wsrc = (t < H) ? (clw + (size_t)t * H) : (nlw + (size_t)(t - H) * H);
        #pragma unroll
        for (int k4 = 0; k4 < H; k4 += 4) {
            float4 v = *(const float4*)(wsrc + k4);
            w[k4] = v.x; w[k4 + 1] = v.y; w[k4 + 2] = v.z; w[k4 + 3] = v.w;
        }
    }
    const float bias = (t < H) ? clb[t] : nlb[t - H];
    const float lg = (t >= H) ? ln_g[t - H] : 0.f;
    const float lb = (t >= H) ? ln_b[t - H] : 0.f;

    const int n0 = blockIdx.x * NPB3;
    for (int nn = 0; nn < NPB3; ++nn) {
        const int node = n0 + nn;
        if (node >= N_NODES) break;            // block-uniform
        const int r0 = rowptr[node], r1 = rowptr[node + 1];

        float pa = 0.f, pe = 0.f;
        for (int j = r0 + par; j < r1; j += 2) {
            const int ee = bucket[j];
            const int sv = bsrc[j];
            pa += qkv[(size_t)sv * QKV_N + 2 * H + col];
            pe += co_f32[(size_t)ee * H + col];
        }
        __syncthreads();
        pa2[t] = pa; pe2[t] = pe;
        __syncthreads();
        if (t < H) ga[t]      = pe2[t] + pe2[t + H];
        else       sa[t - H]  = pa2[t - H] + pa2[t];
        __syncthreads();

        if (t < H) {
            float acc = bias;
            #pragma unroll
            for (int k4 = 0; k4 < H; k4 += 4) {
                float4 c = *(const float4*)(ga + k4);
                acc += c.x * w[k4] + c.y * w[k4 + 1] + c.z * w[k4 + 2] + c.w * w[k4 + 3];
            }
            sa[t] += acc;
        }
        __syncthreads();

        float val = 0.f;
        if (t >= H) {
            const int tt = t - H;
            float acc = bias;
            #pragma unroll
            for (int k4 = 0; k4 < H; k4 += 4) {
                float4 c = *(const float4*)(sa + k4);
                acc += c.x * w[k4] + c.y * w[k4 + 1] + c.z * w[k4 + 2] + c.w * w[k4 + 3];
            }
            val = acc + x[(size_t)node * H + tt];
            red0[tt] = val;
            red1[tt] = val * val;
        }
        __syncthreads();
        if (t < 32) { red0[t] += red0[t + 64]; red1[t] += red1[t + 64]; }
        __syncthreads();
        for (int s = 32; s > 0; s >>= 1) {
            if (t < s) { red0[t] += red0[t + s]; red1[t] += red1[t + s]; }
            __syncthreads();
        }
        if (t >= H) {
            const float mean = red0[0] * (1.f / H);
            const float var  = red1[0] * (1.f / H) - mean * mean;
            const float r    = rsqrtf(var + 1e-5f);
            out_h[(size_t)node * H + (t - H)] = (val - mean) * r * lg + lb;
        }
    }
}

// ---------------------------------------------------------------------------
extern "C" void kernel_launch(void* const* d_in, const int* in_sizes, int n_in,
                              void* d_out, int out_size, void* d_ws, size_t ws_size,
                              hipStream_t stream) {
    const float* x      = (const float*)d_in[0];
    const float* conn   = (const float*)d_in[1];
    const int*   eidx   = (const int*)  d_in[2];
    const float* qkv_w  = (const float*)d_in[3];
    const float* qkv_b  = (const float*)d_in[4];
    const float* e_w    = (const float*)d_in[5];
    const float* e_b    = (const float*)d_in[6];
    const float* clw    = (const float*)d_in[7];
    const float* clb    = (const float*)d_in[8];
    const float* nlw    = (const float*)d_in[9];
    const float* nlb    = (const float*)d_in[10];
    const float* ln_h_g = (const float*)d_in[11];
    const float* ln_h_b = (const float*)d_in[12];
    const float* ln_e_g = (const float*)d_in[13];
    const float* ln_e_b = (const float*)d_in[14];

    float* out_h = (float*)d_out;                        // 50000*96
    float* out_e = out_h + (size_t)N_NODES * H;          // 800000*96

    // ---- ws: qkv | rowptr | hist | bucket | bsrc | dstof | agg | eagg | vbf | cobf
    char* base = (char*)d_ws;
    float* qkv = (float*)base;
    size_t off = (size_t)N_NODES * QKV_N * sizeof(float);        // 57.6 MB
    int* rowptr = (int*)(base + off); off += (size_t)(N_NODES + 1) * 4;
    int* hist   = (int*)(base + off); off += (size_t)N_NODES * 4;
    int* bucket = (int*)(base + off); off += (size_t)N_EDGES * 4;
    int* bsrc   = (int*)(base + off); off += (size_t)N_EDGES * 4;        // 64.4 MB
    int*   dstof = (int*)(base + off);  off += (size_t)N_EDGES * 4;      // 67.6
    float* agg   = (float*)(base + off); off += (size_t)N_NODES * H * 4;
    float* eagg  = (float*)(base + off); off += (size_t)N_NODES * H * 4; // 106 MB
    unsigned short* vbf = (unsigned short*)(base + off);
    off += (size_t)N_NODES * H * 2;                                      // 115.6 MB
    const size_t need_B = off;
    unsigned short* cobf = (unsigned short*)(base + off);
    off += (size_t)N_EDGES * H * 2;                                      // 269.2 MB
    const size_t need_A = off;

    const bool A = ws_size >= need_A;
    const bool B = !A && ws_size >= need_B;

    hipMemsetAsync(hist, 0, (size_t)N_NODES * 4, stream);

    qkv_kernel    <<<(N_NODES + NPB1 - 1) / NPB1, QKV_N, 0, stream>>>(
        x, qkv_w, qkv_b, qkv, (A || B) ? vbf : nullptr);
    hist_kernel   <<<(N_EDGES + 255) / 256, 256, 0, stream>>>(eidx, hist);
    scan_kernel   <<<1, 1024, 0, stream>>>(hist, rowptr);
    scatter_kernel<<<(N_EDGES + 255) / 256, 256, 0, stream>>>(eidx, hist, bucket, bsrc,
                                                              (A || B) ? dstof : nullptr);

    if (A) {
        edge_kernel<true><<<N_EDGES / TILE_E, 256, 0, stream>>>(
            conn, eidx, qkv, e_w, e_b, cobf, out_e);
        // agg with fused edge-LN: writes agg/eagg AND out_e; no eln pass.
        agg_kernel<true, true><<<(N_NODES + NPA - 1) / NPA, 256, 0, stream>>>(
            qkv, vbf, nullptr, cobf, conn, ln_e_g, ln_e_b, out_e,
            rowptr, bucket, bsrc, dstof, agg, eagg);
        node_kernel_big<<<(N_NODES + NPB3B - 1) / NPB3B, 192, 0, stream>>>(
            x, agg, eagg, clw, clb, nlw, nlb, ln_h_g, ln_h_b, out_h);
    } else if (B) {
        edge_kernel<false><<<N_EDGES / TILE_E, 256, 0, stream>>>(
            conn, eidx, qkv, e_w, e_b, nullptr, out_e);
        agg_kernel<true, false><<<(N_NODES + NPA - 1) / NPA, 256, 0, stream>>>(
            qkv, vbf, out_e, nullptr, nullptr, nullptr, nullptr, nullptr,
            rowptr, bucket, bsrc, dstof, agg, eagg);
        node_kernel_big<<<(N_NODES + NPB3B - 1) / NPB3B, 192, 0, stream>>>(
            x, agg, eagg, clw, clb, nlw, nlb, ln_h_g, ln_h_b, out_h);
        eln_kernel<<<(N_EDGES * 4) / 256, 256, 0, stream>>>(
            conn, ln_e_g, ln_e_b, out_e);
    } else {
        edge_kernel<false><<<N_EDGES / TILE_E, 256, 0, stream>>>(
            conn, eidx, qkv, e_w, e_b, nullptr, out_e);
        node_kernel<<<(N_NODES + NPB3 - 1) / NPB3, 192, 0, stream>>>(
            x, qkv, out_e, rowptr, bucket, bsrc,
            clw, clb, nlw, nlb, ln_h_g, ln_h_b, out_h);
        eln_kernel<<<(N_EDGES * 4) / 256, 256, 0, stream>>>(
            conn, ln_e_g, ln_e_b, out_e);
    }
}